// Round 1
// baseline (422.779 us; speedup 1.0000x reference)
//
#include <hip/hip_runtime.h>

#define TOPK 13
#define NCLS 80
#define EPSF 1e-9f

// ---------------------------------------------------------------------------
// Kernel 1: transpose cls_pred (P,80) -> clsT (80,P), staged into the one-hot
// output region of d_out (exactly 80P floats). LDS-tiled, pad 81 to kill bank
// conflicts on the strided LDS read.
// ---------------------------------------------------------------------------
__global__ __launch_bounds__(256) void transpose_cls(const float* __restrict__ cls,
                                                     float* __restrict__ clsT, int P) {
    __shared__ float tile[64 * 81];
    int p0 = blockIdx.x * 64;
    int valid = P - p0; if (valid > 64) valid = 64;
    int lim = valid * NCLS;
    for (int f = threadIdx.x; f < 64 * NCLS; f += 256) {
        int pl = f / NCLS;
        int c  = f - pl * NCLS;
        float v = (f < lim) ? cls[(size_t)p0 * NCLS + f] : 0.0f;
        tile[pl * 81 + c] = v;
    }
    __syncthreads();
    for (int f = threadIdx.x; f < 64 * NCLS; f += 256) {
        int c = f >> 6;       // 0..79
        int j = f & 63;       // 0..63
        if (j < valid) clsT[(size_t)c * P + p0 + j] = tile[j * 81 + c];
    }
}

// ---------------------------------------------------------------------------
// Kernel 2: per-GT top-13 of metric = score * iou^6 over all P priors.
// One block per GT (512 threads). Thread-local sorted top-13 (branchless,
// fully unrolled -> stays in VGPRs), then LDS tree-merge. Winners scattered
// via atomics into count[] / firstg[] (device scope).
// ---------------------------------------------------------------------------
__global__ __launch_bounds__(512) void phaseA(const float* __restrict__ clsT,
                                              const float4* __restrict__ bboxp,
                                              const float4* __restrict__ bboxg,
                                              const int* __restrict__ lbl,
                                              int* __restrict__ count,
                                              int* __restrict__ firstg, int P) {
#pragma clang fp contract(off)
    const int g = blockIdx.x;
    const float4 gb = bboxg[g];
    const int c = lbl[g] - 1;
    const float garea = fmaxf(gb.z - gb.x, 0.0f) * fmaxf(gb.w - gb.y, 0.0f);
    const float* crow = clsT + (size_t)c * P;

    float v[TOPK]; int id[TOPK];
#pragma unroll
    for (int j = 0; j < TOPK; j++) { v[j] = -1.0f; id[j] = 0; }

#pragma unroll 2
    for (int p = threadIdx.x; p < P; p += 512) {
        float4 pb = bboxp[p];
        float score = crow[p];
        float xx1 = fmaxf(gb.x, pb.x), yy1 = fmaxf(gb.y, pb.y);
        float xx2 = fminf(gb.z, pb.z), yy2 = fminf(gb.w, pb.w);
        float inter = fmaxf(xx2 - xx1, 0.0f) * fmaxf(yy2 - yy1, 0.0f);
        float parea = fmaxf(pb.z - pb.x, 0.0f) * fmaxf(pb.w - pb.y, 0.0f);
        float iou = inter / (((garea + parea) - inter) + EPSF);
        float i2 = iou * iou;
        float i6 = (i2 * i2) * i2;
        float m = score * i6;
        if (m > v[TOPK - 1]) {
            // branchless sorted insert (descending), fully unrolled
#pragma unroll
            for (int j = TOPK - 1; j >= 1; j--) {
                bool a = m > v[j - 1];
                bool b = m > v[j];
                float nv = a ? v[j - 1] : (b ? m : v[j]);
                int   ni = a ? id[j - 1] : (b ? p : id[j]);
                v[j] = nv; id[j] = ni;
            }
            if (m > v[0]) { v[0] = m; id[0] = p; }
        }
    }

    __shared__ float sv[512 * TOPK];
    __shared__ int   si[512 * TOPK];
#pragma unroll
    for (int j = 0; j < TOPK; j++) {
        sv[threadIdx.x * TOPK + j] = v[j];
        si[threadIdx.x * TOPK + j] = id[j];
    }
    __syncthreads();
    for (int stride = 256; stride >= 1; stride >>= 1) {
        if (threadIdx.x < (unsigned)stride) {
            float* va = &sv[threadIdx.x * TOPK];
            int*   ia = &si[threadIdx.x * TOPK];
            float* vb = &sv[(threadIdx.x + stride) * TOPK];
            int*   ib = &si[(threadIdx.x + stride) * TOPK];
            float mv[TOPK]; int mi[TOPK];
            int a = 0, b = 0;
#pragma unroll
            for (int j = 0; j < TOPK; j++) {
                float fa = va[a], fb = vb[b];
                if (fa >= fb) { mv[j] = fa; mi[j] = ia[a]; a++; }
                else          { mv[j] = fb; mi[j] = ib[b]; b++; }
            }
#pragma unroll
            for (int j = 0; j < TOPK; j++) { va[j] = mv[j]; ia[j] = mi[j]; }
        }
        __syncthreads();
    }
    // keep condition: row max > eps; else the row contributes nothing
    if (threadIdx.x < TOPK && sv[0] > EPSF) {
        int pi = si[threadIdx.x];
        atomicAdd(&count[pi], 1);
        atomicMin(&firstg[pi], g);
    }
}

// ---------------------------------------------------------------------------
// Kernel 3 (C1): per-prior resolve -> gt_index + label outputs.
// count==0 -> gi=0, label 0. count==1 -> gi=firstg. count>1 -> iou-argmax
// over ALL GTs (first-max), label=lbl[gi].
// ---------------------------------------------------------------------------
__global__ __launch_bounds__(256) void phaseC1(const float4* __restrict__ bboxp,
                                               const float4* __restrict__ bboxg,
                                               const int* __restrict__ lbl,
                                               const int* __restrict__ count,
                                               const int* __restrict__ firstg,
                                               float* __restrict__ out0,
                                               float* __restrict__ out1, int P, int N) {
#pragma clang fp contract(off)
    __shared__ float4 gbS[256];
    __shared__ int glS[256];
    if (threadIdx.x < (unsigned)N) {
        gbS[threadIdx.x] = bboxg[threadIdx.x];
        glS[threadIdx.x] = lbl[threadIdx.x];
    }
    __syncthreads();
    int p = blockIdx.x * 256 + threadIdx.x;
    if (p >= P) return;
    int cnt = count[p];
    int gi = 0, pos = 0;
    if (cnt == 1) { gi = firstg[p]; pos = 1; }
    else if (cnt > 1) {
        float4 pb = bboxp[p];
        float parea = fmaxf(pb.z - pb.x, 0.0f) * fmaxf(pb.w - pb.y, 0.0f);
        float best = -1.0f;
        for (int g = 0; g < N; g++) {
            float4 g4 = gbS[g];
            float garea = fmaxf(g4.z - g4.x, 0.0f) * fmaxf(g4.w - g4.y, 0.0f);
            float xx1 = fmaxf(g4.x, pb.x), yy1 = fmaxf(g4.y, pb.y);
            float xx2 = fminf(g4.z, pb.z), yy2 = fminf(g4.w, pb.w);
            float inter = fmaxf(xx2 - xx1, 0.0f) * fmaxf(yy2 - yy1, 0.0f);
            float iou = inter / (((garea + parea) - inter) + EPSF);
            if (iou > best) { best = iou; gi = g; }  // strict > == first-max
        }
        pos = 1;
    }
    out0[p] = (float)gi;
    out1[p] = pos ? (float)glS[gi] : 0.0f;
}

// ---------------------------------------------------------------------------
// Kernel 4 (C2): write one-hot (80P) and assigned bboxes (4P), fully
// coalesced block-cooperative writes. Reads gi back from out0. Overwrites the
// clsT / count / firstg scratch regions (all already consumed).
// ---------------------------------------------------------------------------
__global__ __launch_bounds__(256) void phaseC2(const float4* __restrict__ bboxg,
                                               const int* __restrict__ lbl,
                                               const float* __restrict__ out0,
                                               float* __restrict__ outcls,
                                               float* __restrict__ outbox, int P, int N) {
    __shared__ float gbb[256 * 4];
    __shared__ int glS[256];
    __shared__ int clsl[256];
    __shared__ int gil[256];
    int tid = threadIdx.x;
    if (tid < N) {
        float4 b = bboxg[tid];
        gbb[tid * 4 + 0] = b.x; gbb[tid * 4 + 1] = b.y;
        gbb[tid * 4 + 2] = b.z; gbb[tid * 4 + 3] = b.w;
        glS[tid] = lbl[tid];
    }
    __syncthreads();
    int p0 = blockIdx.x * 256;
    int nloc = P - p0; if (nloc > 256) nloc = 256;
    if (tid < nloc) {
        int gi = (int)out0[p0 + tid];
        gil[tid] = gi;
        clsl[tid] = glS[gi] - 1;   // always valid in [0,79] (pre-zeroed label)
    }
    __syncthreads();
    for (int f = tid; f < nloc * NCLS; f += 256) {
        int pl = f / NCLS;
        int c  = f - pl * NCLS;
        outcls[(size_t)p0 * NCLS + f] = (c == clsl[pl]) ? 1.0f : 0.0f;
    }
    for (int f = tid; f < nloc * 4; f += 256) {
        int pl = f >> 2, k = f & 3;
        outbox[(size_t)p0 * 4 + f] = gbb[gil[pl] * 4 + k];
    }
}

extern "C" void kernel_launch(void* const* d_in, const int* in_sizes, int n_in,
                              void* d_out, int out_size, void* d_ws, size_t ws_size,
                              hipStream_t stream) {
    const float* cls_pred  = (const float*)d_in[0];
    const float* bbox_pred = (const float*)d_in[1];
    const int*   label_gt  = (const int*)d_in[2];
    const float* bbox_gt   = (const float*)d_in[3];
    int P = in_sizes[1] / 4;
    int N = in_sizes[3] / 4;

    float* out    = (float*)d_out;
    float* out0   = out;                      // [0,P)    gt_index
    float* out1   = out + (size_t)P;          // [P,2P)   labels
    float* outcls = out + (size_t)2 * P;      // [2P,82P) one-hot (scratch: clsT)
    float* outbox = out + (size_t)82 * P;     // [82P,86P) bboxes (scratch: count/firstg)
    int* count  = (int*)outbox;               // P ints
    int* firstg = ((int*)outbox) + P;         // P ints, init 0x7F7F7F7F > any g

    hipMemsetAsync(count, 0, (size_t)P * sizeof(int), stream);
    hipMemsetAsync(firstg, 0x7F, (size_t)P * sizeof(int), stream);

    int tb = (P + 63) / 64;
    transpose_cls<<<tb, 256, 0, stream>>>(cls_pred, outcls, P);
    phaseA<<<N, 512, 0, stream>>>(outcls, (const float4*)bbox_pred,
                                  (const float4*)bbox_gt, label_gt, count, firstg, P);
    int pb = (P + 255) / 256;
    phaseC1<<<pb, 256, 0, stream>>>((const float4*)bbox_pred, (const float4*)bbox_gt,
                                    label_gt, count, firstg, out0, out1, P, N);
    phaseC2<<<pb, 256, 0, stream>>>((const float4*)bbox_gt, label_gt, out0,
                                    outcls, outbox, P, N);
}

// Round 2
// 333.563 us; speedup vs baseline: 1.2675x; 1.2675x over previous
//
#include <hip/hip_runtime.h>

#define TOPK 13
#define NCLS 80
#define EPSF 1e-9f
#define NSEG 8

// ---------------------------------------------------------------------------
// Kernel 1 (prep): transpose cls_pred (P,80) -> clsT (80,P) staged into the
// one-hot output region, and precompute parea[p] staged into out0 region
// (consumed by phaseA1 before phaseC1 overwrites out0).
// ---------------------------------------------------------------------------
__global__ __launch_bounds__(256) void prep(const float* __restrict__ cls,
                                            const float4* __restrict__ bboxp,
                                            float* __restrict__ clsT,
                                            float* __restrict__ parea, int P) {
#pragma clang fp contract(off)
    __shared__ float tile[64 * 81];
    int p0 = blockIdx.x * 64;
    int valid = P - p0; if (valid > 64) valid = 64;
    int lim = valid * NCLS;
    for (int f = threadIdx.x; f < 64 * NCLS; f += 256) {
        int pl = f / NCLS;
        int c  = f - pl * NCLS;
        float v = (f < lim) ? cls[(size_t)p0 * NCLS + f] : 0.0f;
        tile[pl * 81 + c] = v;
    }
    if ((int)threadIdx.x < valid) {
        float4 pb = bboxp[p0 + threadIdx.x];
        parea[p0 + threadIdx.x] = fmaxf(pb.z - pb.x, 0.0f) * fmaxf(pb.w - pb.y, 0.0f);
    }
    __syncthreads();
    for (int f = threadIdx.x; f < 64 * NCLS; f += 256) {
        int c = f >> 6;       // 0..79
        int j = f & 63;       // 0..63
        if (j < valid) clsT[(size_t)c * P + p0 + j] = tile[j * 81 + c];
    }
}

// ---------------------------------------------------------------------------
// Kernel 2 (A1): per (GT, segment) top-13 of metric = score * iou^6.
// Grid (NSEG, N), 256 threads. Thread-local sorted top-13 in VGPRs, LDS
// tree-merge with (value desc, index asc) tie-break, write 13 candidates
// per (g,s) to scratch.
// ---------------------------------------------------------------------------
__global__ __launch_bounds__(256) void phaseA1(const float* __restrict__ clsT,
                                               const float4* __restrict__ bboxp,
                                               const float* __restrict__ parea,
                                               const float4* __restrict__ bboxg,
                                               const int* __restrict__ lbl,
                                               float2* __restrict__ cand,
                                               int P, int seglen) {
#pragma clang fp contract(off)
    const int s = blockIdx.x;
    const int g = blockIdx.y;
    int pstart = s * seglen;
    int pend = pstart + seglen; if (pend > P) pend = P;
    const float4 gb = bboxg[g];
    const int c = lbl[g] - 1;
    const float garea = fmaxf(gb.z - gb.x, 0.0f) * fmaxf(gb.w - gb.y, 0.0f);
    const float* crow = clsT + (size_t)c * P;

    float v[TOPK]; int id[TOPK];
#pragma unroll
    for (int j = 0; j < TOPK; j++) { v[j] = -1.0f; id[j] = 0x7FFFFFFF; }

    for (int p = pstart + threadIdx.x; p < pend; p += 256) {
        float4 pb = bboxp[p];
        float score = crow[p];
        float pa = parea[p];
        float xx1 = fmaxf(gb.x, pb.x), yy1 = fmaxf(gb.y, pb.y);
        float xx2 = fminf(gb.z, pb.z), yy2 = fminf(gb.w, pb.w);
        float inter = fmaxf(xx2 - xx1, 0.0f) * fmaxf(yy2 - yy1, 0.0f);
        float iou = inter / (((garea + pa) - inter) + EPSF);
        float i2 = iou * iou;
        float i6 = (i2 * i2) * i2;
        float m = score * i6;
        if (m > v[TOPK - 1]) {
            // branchless sorted insert (descending); strict > keeps earlier
            // (lower p within thread) on ties -> min-index tie rule
#pragma unroll
            for (int j = TOPK - 1; j >= 1; j--) {
                bool a = m > v[j - 1];
                bool b = m > v[j];
                float nv = a ? v[j - 1] : (b ? m : v[j]);
                int   ni = a ? id[j - 1] : (b ? p : id[j]);
                v[j] = nv; id[j] = ni;
            }
            if (m > v[0]) { v[0] = m; id[0] = p; }
        }
    }

    __shared__ float sv[256 * TOPK];
    __shared__ int   si[256 * TOPK];
#pragma unroll
    for (int j = 0; j < TOPK; j++) {
        sv[threadIdx.x * TOPK + j] = v[j];
        si[threadIdx.x * TOPK + j] = id[j];
    }
    __syncthreads();
    for (int stride = 128; stride >= 1; stride >>= 1) {
        if ((int)threadIdx.x < stride) {
            float* va = &sv[threadIdx.x * TOPK];
            int*   ia = &si[threadIdx.x * TOPK];
            float* vb = &sv[(threadIdx.x + stride) * TOPK];
            int*   ib = &si[(threadIdx.x + stride) * TOPK];
            float mv[TOPK]; int mi[TOPK];
            int a = 0, b = 0;
#pragma unroll
            for (int j = 0; j < TOPK; j++) {
                float fa = va[a], fb = vb[b];
                int   xa = ia[a], xb = ib[b];
                bool takeA = (fa > fb) || (fa == fb && xa < xb);
                if (takeA) { mv[j] = fa; mi[j] = xa; a++; }
                else       { mv[j] = fb; mi[j] = xb; b++; }
            }
#pragma unroll
            for (int j = 0; j < TOPK; j++) { va[j] = mv[j]; ia[j] = mi[j]; }
        }
        __syncthreads();
    }
    if (threadIdx.x < TOPK) {
        cand[((size_t)g * NSEG + s) * TOPK + threadIdx.x] =
            make_float2(sv[threadIdx.x], __int_as_float(si[threadIdx.x]));
    }
}

// ---------------------------------------------------------------------------
// Kernel 3 (A2): per GT merge NSEG*13=104 candidates -> exact global top-13
// via 128-element bitonic sort with (value desc, index asc) order, then
// scatter count/firstg atomics if row max > eps.
// ---------------------------------------------------------------------------
__global__ __launch_bounds__(128) void phaseA2(const float2* __restrict__ cand,
                                               int* __restrict__ count,
                                               int* __restrict__ firstg) {
    const int g = blockIdx.x;
    const int t = threadIdx.x;
    const int M = NSEG * TOPK;  // 104
    __shared__ float cv[128];
    __shared__ int   ci[128];
    if (t < M) {
        float2 e = cand[(size_t)g * M + t];
        cv[t] = e.x; ci[t] = __float_as_int(e.y);
    } else {
        cv[t] = -1.0f; ci[t] = 0x7FFFFFFF;
    }
    __syncthreads();
    for (int k = 2; k <= 128; k <<= 1) {
        for (int j = k >> 1; j >= 1; j >>= 1) {
            int ixj = t ^ j;
            if (ixj > t) {
                float va = cv[t], vb = cv[ixj];
                int   ia = ci[t], ib = ci[ixj];
                bool aBeforeB = (va > vb) || (va == vb && ia < ib);
                bool dirFwd = ((t & k) == 0);   // forward = best-first
                bool doswap = dirFwd ? !aBeforeB : aBeforeB;
                if (doswap) { cv[t] = vb; ci[t] = ib; cv[ixj] = va; ci[ixj] = ia; }
            }
            __syncthreads();
        }
    }
    if (t < TOPK && cv[0] > EPSF) {
        int pi = ci[t];
        atomicAdd(&count[pi], 1);
        atomicMin(&firstg[pi], g);
    }
}

// ---------------------------------------------------------------------------
// Kernel 4 (C1): per-prior resolve -> gt_index + label outputs.
// ---------------------------------------------------------------------------
__global__ __launch_bounds__(256) void phaseC1(const float4* __restrict__ bboxp,
                                               const float4* __restrict__ bboxg,
                                               const int* __restrict__ lbl,
                                               const int* __restrict__ count,
                                               const int* __restrict__ firstg,
                                               float* __restrict__ out0,
                                               float* __restrict__ out1, int P, int N) {
#pragma clang fp contract(off)
    __shared__ float4 gbS[256];
    __shared__ int glS[256];
    if (threadIdx.x < (unsigned)N) {
        gbS[threadIdx.x] = bboxg[threadIdx.x];
        glS[threadIdx.x] = lbl[threadIdx.x];
    }
    __syncthreads();
    int p = blockIdx.x * 256 + threadIdx.x;
    if (p >= P) return;
    int cnt = count[p];
    int gi = 0, pos = 0;
    if (cnt == 1) { gi = firstg[p]; pos = 1; }
    else if (cnt > 1) {
        float4 pb = bboxp[p];
        float parea = fmaxf(pb.z - pb.x, 0.0f) * fmaxf(pb.w - pb.y, 0.0f);
        float best = -1.0f;
        for (int g = 0; g < N; g++) {
            float4 g4 = gbS[g];
            float garea = fmaxf(g4.z - g4.x, 0.0f) * fmaxf(g4.w - g4.y, 0.0f);
            float xx1 = fmaxf(g4.x, pb.x), yy1 = fmaxf(g4.y, pb.y);
            float xx2 = fminf(g4.z, pb.z), yy2 = fminf(g4.w, pb.w);
            float inter = fmaxf(xx2 - xx1, 0.0f) * fmaxf(yy2 - yy1, 0.0f);
            float iou = inter / (((garea + parea) - inter) + EPSF);
            if (iou > best) { best = iou; gi = g; }  // strict > == first-max
        }
        pos = 1;
    }
    out0[p] = (float)gi;
    out1[p] = pos ? (float)glS[gi] : 0.0f;
}

// ---------------------------------------------------------------------------
// Kernel 5 (C2): write one-hot (80P) and assigned bboxes (4P), coalesced.
// Overwrites the clsT / count / firstg / cand scratch (already consumed).
// ---------------------------------------------------------------------------
__global__ __launch_bounds__(256) void phaseC2(const float4* __restrict__ bboxg,
                                               const int* __restrict__ lbl,
                                               const float* __restrict__ out0,
                                               float* __restrict__ outcls,
                                               float* __restrict__ outbox, int P, int N) {
    __shared__ float gbb[256 * 4];
    __shared__ int glS[256];
    __shared__ int clsl[256];
    __shared__ int gil[256];
    int tid = threadIdx.x;
    if (tid < N) {
        float4 b = bboxg[tid];
        gbb[tid * 4 + 0] = b.x; gbb[tid * 4 + 1] = b.y;
        gbb[tid * 4 + 2] = b.z; gbb[tid * 4 + 3] = b.w;
        glS[tid] = lbl[tid];
    }
    __syncthreads();
    int p0 = blockIdx.x * 256;
    int nloc = P - p0; if (nloc > 256) nloc = 256;
    if (tid < nloc) {
        int gi = (int)out0[p0 + tid];
        gil[tid] = gi;
        clsl[tid] = glS[gi] - 1;   // always in [0,79] (pre-zeroed label)
    }
    __syncthreads();
    for (int f = tid; f < nloc * NCLS; f += 256) {
        int pl = f / NCLS;
        int c  = f - pl * NCLS;
        outcls[(size_t)p0 * NCLS + f] = (c == clsl[pl]) ? 1.0f : 0.0f;
    }
    for (int f = tid; f < nloc * 4; f += 256) {
        int pl = f >> 2, k = f & 3;
        outbox[(size_t)p0 * 4 + f] = gbb[gil[pl] * 4 + k];
    }
}

extern "C" void kernel_launch(void* const* d_in, const int* in_sizes, int n_in,
                              void* d_out, int out_size, void* d_ws, size_t ws_size,
                              hipStream_t stream) {
    const float* cls_pred  = (const float*)d_in[0];
    const float* bbox_pred = (const float*)d_in[1];
    const int*   label_gt  = (const int*)d_in[2];
    const float* bbox_gt   = (const float*)d_in[3];
    int P = in_sizes[1] / 4;
    int N = in_sizes[3] / 4;

    float* out    = (float*)d_out;
    float* out0   = out;                      // [0,P)    gt_index (scratch: parea)
    float* out1   = out + (size_t)P;          // [P,2P)   labels
    float* outcls = out + (size_t)2 * P;      // [2P,82P) one-hot (scratch: clsT)
    float* outbox = out + (size_t)82 * P;     // [82P,86P) bboxes (scratch below)
    int*    count  = (int*)outbox;            // P ints
    int*    firstg = ((int*)outbox) + P;      // P ints, init 0x7F7F7F7F > any g
    float2* cand   = (float2*)(((int*)outbox) + 2 * (size_t)P);  // N*NSEG*13 float2

    hipMemsetAsync(count, 0, (size_t)P * sizeof(int), stream);
    hipMemsetAsync(firstg, 0x7F, (size_t)P * sizeof(int), stream);

    int tb = (P + 63) / 64;
    prep<<<tb, 256, 0, stream>>>(cls_pred, (const float4*)bbox_pred, outcls, out0, P);

    int seglen = (P + NSEG - 1) / NSEG;
    dim3 gridA1(NSEG, N);
    phaseA1<<<gridA1, 256, 0, stream>>>(outcls, (const float4*)bbox_pred, out0,
                                        (const float4*)bbox_gt, label_gt, cand, P, seglen);
    phaseA2<<<N, 128, 0, stream>>>(cand, count, firstg);

    int pb = (P + 255) / 256;
    phaseC1<<<pb, 256, 0, stream>>>((const float4*)bbox_pred, (const float4*)bbox_gt,
                                    label_gt, count, firstg, out0, out1, P, N);
    phaseC2<<<pb, 256, 0, stream>>>((const float4*)bbox_gt, label_gt, out0,
                                    outcls, outbox, P, N);
}

// Round 3
// 279.766 us; speedup vs baseline: 1.5112x; 1.1923x over previous
//
#include <hip/hip_runtime.h>

#define TOPK 13
#define NCLS 80
#define EPSF 1e-9f
#define NSEG 8
#define CAP  3328   // 256*13 entries; buffer doubles as merge scratch

// ---------------------------------------------------------------------------
// prep: transpose cls_pred (P,80) -> clsT (80,P); parea[p]; zero count/firstg.
// ---------------------------------------------------------------------------
__global__ __launch_bounds__(256) void prep(const float4* __restrict__ cls4,
                                            const float4* __restrict__ bboxp,
                                            float* __restrict__ clsT,
                                            float* __restrict__ parea,
                                            int* __restrict__ count,
                                            int* __restrict__ firstg, int P) {
#pragma clang fp contract(off)
    __shared__ float tile[64 * 81];
    int p0 = blockIdx.x * 64;
    int valid = P - p0; if (valid > 64) valid = 64;
    int t = threadIdx.x;
    // load 64 rows x 80 cols as float4 (1280 per block), scatter to padded tile
    int limq = valid * 20;
    for (int f = t; f < 64 * 20; f += 256) {
        int pl = f / 20, cq = f - pl * 20;
        float4 v = (f < limq) ? cls4[(size_t)p0 * 20 + f] : make_float4(0, 0, 0, 0);
        tile[pl * 81 + 4 * cq + 0] = v.x;
        tile[pl * 81 + 4 * cq + 1] = v.y;
        tile[pl * 81 + 4 * cq + 2] = v.z;
        tile[pl * 81 + 4 * cq + 3] = v.w;
    }
    if (t < valid) {
        float4 pb = bboxp[p0 + t];
        parea[p0 + t] = fmaxf(pb.z - pb.x, 0.0f) * fmaxf(pb.w - pb.y, 0.0f);
    }
    if (t < 64 && t < valid) { count[p0 + t] = 0; firstg[p0 + t] = 0x7FFFFFFF; }
    __syncthreads();
    // write clsT as float4: thread handles (c, j4): rows c, 4 consecutive priors
    for (int f = t; f < 80 * 16; f += 256) {
        int c = f >> 4, j4 = f & 15;
        int j = 4 * j4;
        if (j < valid) {
            float4 o;
            o.x = tile[(j + 0) * 81 + c];
            o.y = tile[(j + 1) * 81 + c];
            o.z = tile[(j + 2) * 81 + c];
            o.w = tile[(j + 3) * 81 + c];
            *(float4*)&clsT[(size_t)c * P + p0 + j] = o;
        }
    }
}

// ---------------------------------------------------------------------------
// phaseA1: per (segment, GT): compact candidates (m>0, plus first 256 elems)
// into LDS, then exact top-13 selection with (value desc, index asc) ties.
// Overflow (>CAP appends) -> exact full-rescan fallback (cold).
// ---------------------------------------------------------------------------
__global__ __launch_bounds__(256) void phaseA1(const float* __restrict__ clsT,
                                               const float4* __restrict__ bboxp,
                                               const float* __restrict__ parea,
                                               const float4* __restrict__ bboxg,
                                               const int* __restrict__ lbl,
                                               float2* __restrict__ cand,
                                               int P, int seglen) {
#pragma clang fp contract(off)
    const int s = blockIdx.x, g = blockIdx.y, t = threadIdx.x;
    const int pstart = s * seglen;
    int pend = pstart + seglen; if (pend > P) pend = P;
    const float4 gb = bboxg[g];
    const int c = lbl[g] - 1;
    const float garea = fmaxf(gb.z - gb.x, 0.0f) * fmaxf(gb.w - gb.y, 0.0f);
    const float* crow = clsT + (size_t)c * P;

    __shared__ int smem[2 * CAP];     // float2 buf[CAP], later sv/si
    __shared__ int ctr;
    float2* buf = (float2*)smem;
    if (t == 0) ctr = 0;
    __syncthreads();

    const int lane = t & 63;
    const unsigned long long lanemask = (lane == 63) ? ~0ull : ((1ull << (lane + 1)) - 1ull);
    bool first = true;
    for (int p = pstart + t; p < pend; p += 256) {
        float4 pb = bboxp[p];
        float sc = crow[p];
        float pa = parea[p];
        float xx1 = fmaxf(gb.x, pb.x), yy1 = fmaxf(gb.y, pb.y);
        float xx2 = fminf(gb.z, pb.z), yy2 = fminf(gb.w, pb.w);
        float inter = fmaxf(xx2 - xx1, 0.0f) * fmaxf(yy2 - yy1, 0.0f);
        float iou = inter / (((garea + pa) - inter) + EPSF);
        float i2 = iou * iou;
        float m = sc * ((i2 * i2) * i2);
        bool want = (m > 0.0f) || first;
        first = false;
        unsigned long long mask = __ballot(want);
        if (mask) {
            int leader = __ffsll((unsigned long long)mask) - 1;
            int nsel = __popcll(mask);
            int base = 0;
            if (lane == leader) base = atomicAdd(&ctr, nsel);
            base = __shfl(base, leader);
            if (want) {
                int slot = base + __popcll(mask & lanemask) - 1;
                if (slot < CAP) buf[slot] = make_float2(m, __int_as_float(p));
            }
        }
    }
    __syncthreads();
    int total = ctr;

    float v[TOPK]; int id[TOPK];
#pragma unroll
    for (int j = 0; j < TOPK; j++) { v[j] = -1.0f; id[j] = 0x7FFFFFFF; }

    if (total <= CAP) {
        // selection from compacted buffer
        for (int e = t; e < total; e += 256) {
            float2 E = buf[e];
            float m = E.x; int p = __float_as_int(E.y);
            bool b12 = (m > v[TOPK - 1]) || (m == v[TOPK - 1] && p < id[TOPK - 1]);
            if (b12) {
#pragma unroll
                for (int j = TOPK - 1; j >= 1; j--) {
                    bool a = (m > v[j - 1]) || (m == v[j - 1] && p < id[j - 1]);
                    bool b = (m > v[j]) || (m == v[j] && p < id[j]);
                    float nv = a ? v[j - 1] : (b ? m : v[j]);
                    int   ni = a ? id[j - 1] : (b ? p : id[j]);
                    v[j] = nv; id[j] = ni;
                }
                bool a0 = (m > v[0]) || (m == v[0] && p < id[0]);
                if (a0) { v[0] = m; id[0] = p; }
            }
        }
    } else {
        // overflow fallback: exact rescan (never taken for this input)
        for (int p = pstart + t; p < pend; p += 256) {
            float4 pb = bboxp[p];
            float sc = crow[p];
            float pa = parea[p];
            float xx1 = fmaxf(gb.x, pb.x), yy1 = fmaxf(gb.y, pb.y);
            float xx2 = fminf(gb.z, pb.z), yy2 = fminf(gb.w, pb.w);
            float inter = fmaxf(xx2 - xx1, 0.0f) * fmaxf(yy2 - yy1, 0.0f);
            float iou = inter / (((garea + pa) - inter) + EPSF);
            float i2 = iou * iou;
            float m = sc * ((i2 * i2) * i2);
            bool b12 = (m > v[TOPK - 1]) || (m == v[TOPK - 1] && p < id[TOPK - 1]);
            if (b12) {
#pragma unroll
                for (int j = TOPK - 1; j >= 1; j--) {
                    bool a = (m > v[j - 1]) || (m == v[j - 1] && p < id[j - 1]);
                    bool b = (m > v[j]) || (m == v[j] && p < id[j]);
                    float nv = a ? v[j - 1] : (b ? m : v[j]);
                    int   ni = a ? id[j - 1] : (b ? p : id[j]);
                    v[j] = nv; id[j] = ni;
                }
                bool a0 = (m > v[0]) || (m == v[0] && p < id[0]);
                if (a0) { v[0] = m; id[0] = p; }
            }
        }
    }
    __syncthreads();  // all buffer reads done before overwrite

    float* sv = (float*)smem;        // [0, CAP)
    int*   si = smem + CAP;          // [CAP, 2*CAP)
#pragma unroll
    for (int j = 0; j < TOPK; j++) {
        sv[t * TOPK + j] = v[j];
        si[t * TOPK + j] = id[j];
    }
    __syncthreads();
    for (int stride = 128; stride >= 1; stride >>= 1) {
        if (t < stride) {
            float* va = &sv[t * TOPK];
            int*   ia = &si[t * TOPK];
            float* vb = &sv[(t + stride) * TOPK];
            int*   ib = &si[(t + stride) * TOPK];
            float mv[TOPK]; int mi[TOPK];
            int a = 0, b = 0;
#pragma unroll
            for (int j = 0; j < TOPK; j++) {
                float fa = va[a], fb = vb[b];
                int   xa = ia[a], xb = ib[b];
                bool takeA = (fa > fb) || (fa == fb && xa < xb);
                if (takeA) { mv[j] = fa; mi[j] = xa; a++; }
                else       { mv[j] = fb; mi[j] = xb; b++; }
            }
#pragma unroll
            for (int j = 0; j < TOPK; j++) { va[j] = mv[j]; ia[j] = mi[j]; }
        }
        __syncthreads();
    }
    if (t < TOPK) {
        cand[((size_t)g * NSEG + s) * TOPK + t] =
            make_float2(sv[t], __int_as_float(si[t]));
    }
}

// ---------------------------------------------------------------------------
// phaseA2: merge NSEG*13=104 candidates/GT -> global top-13, scatter atomics.
// ---------------------------------------------------------------------------
__global__ __launch_bounds__(128) void phaseA2(const float2* __restrict__ cand,
                                               int* __restrict__ count,
                                               int* __restrict__ firstg) {
    const int g = blockIdx.x;
    const int t = threadIdx.x;
    const int M = NSEG * TOPK;  // 104
    __shared__ float cv[128];
    __shared__ int   ci[128];
    if (t < M) {
        float2 e = cand[(size_t)g * M + t];
        cv[t] = e.x; ci[t] = __float_as_int(e.y);
    } else {
        cv[t] = -1.0f; ci[t] = 0x7FFFFFFF;
    }
    __syncthreads();
    for (int k = 2; k <= 128; k <<= 1) {
        for (int j = k >> 1; j >= 1; j >>= 1) {
            int ixj = t ^ j;
            if (ixj > t) {
                float va = cv[t], vb = cv[ixj];
                int   ia = ci[t], ib = ci[ixj];
                bool aBeforeB = (va > vb) || (va == vb && ia < ib);
                bool dirFwd = ((t & k) == 0);
                bool doswap = dirFwd ? !aBeforeB : aBeforeB;
                if (doswap) { cv[t] = vb; ci[t] = ib; cv[ixj] = va; ci[ixj] = ia; }
            }
            __syncthreads();
        }
    }
    if (t < TOPK && cv[0] > EPSF) {
        int pi = ci[t];
        atomicAdd(&count[pi], 1);
        atomicMin(&firstg[pi], g);
    }
}

// ---------------------------------------------------------------------------
// phaseC (fused, ws path): resolve + all outputs. One-hot region pre-zeroed
// by memset; only the 1.0 per prior is scattered.
// ---------------------------------------------------------------------------
__global__ __launch_bounds__(256) void phaseC(const float4* __restrict__ bboxp,
                                              const float4* __restrict__ bboxg,
                                              const int* __restrict__ lbl,
                                              const int* __restrict__ count,
                                              const int* __restrict__ firstg,
                                              float* __restrict__ out0,
                                              float* __restrict__ out1,
                                              float* __restrict__ outcls,
                                              float4* __restrict__ outbox, int P, int N) {
#pragma clang fp contract(off)
    __shared__ float4 gbS[256];
    __shared__ int glS[256];
    int t = threadIdx.x;
    if (t < N) { gbS[t] = bboxg[t]; glS[t] = lbl[t]; }
    __syncthreads();
    int p = blockIdx.x * 256 + t;
    if (p >= P) return;
    int cnt = count[p];
    int gi = 0, pos = 0;
    if (cnt == 1) { gi = firstg[p]; pos = 1; }
    else if (cnt > 1) {
        float4 pb = bboxp[p];
        float pa = fmaxf(pb.z - pb.x, 0.0f) * fmaxf(pb.w - pb.y, 0.0f);
        float best = -1.0f;
        for (int g = 0; g < N; g++) {
            float4 g4 = gbS[g];
            float ga = fmaxf(g4.z - g4.x, 0.0f) * fmaxf(g4.w - g4.y, 0.0f);
            float xx1 = fmaxf(g4.x, pb.x), yy1 = fmaxf(g4.y, pb.y);
            float xx2 = fminf(g4.z, pb.z), yy2 = fminf(g4.w, pb.w);
            float inter = fmaxf(xx2 - xx1, 0.0f) * fmaxf(yy2 - yy1, 0.0f);
            float iou = inter / (((ga + pa) - inter) + EPSF);
            if (iou > best) { best = iou; gi = g; }
        }
        pos = 1;
    }
    out0[p] = (float)gi;
    out1[p] = pos ? (float)glS[gi] : 0.0f;
    outcls[(size_t)p * NCLS + (glS[gi] - 1)] = 1.0f;
    outbox[p] = gbS[gi];
}

// ---------------------------------------------------------------------------
// Fallback path kernels (ws too small): round-2 C1 + C2 (dense writes).
// ---------------------------------------------------------------------------
__global__ __launch_bounds__(256) void phaseC1(const float4* __restrict__ bboxp,
                                               const float4* __restrict__ bboxg,
                                               const int* __restrict__ lbl,
                                               const int* __restrict__ count,
                                               const int* __restrict__ firstg,
                                               float* __restrict__ out0,
                                               float* __restrict__ out1, int P, int N) {
#pragma clang fp contract(off)
    __shared__ float4 gbS[256];
    __shared__ int glS[256];
    if (threadIdx.x < (unsigned)N) {
        gbS[threadIdx.x] = bboxg[threadIdx.x];
        glS[threadIdx.x] = lbl[threadIdx.x];
    }
    __syncthreads();
    int p = blockIdx.x * 256 + threadIdx.x;
    if (p >= P) return;
    int cnt = count[p];
    int gi = 0, pos = 0;
    if (cnt == 1) { gi = firstg[p]; pos = 1; }
    else if (cnt > 1) {
        float4 pb = bboxp[p];
        float pa = fmaxf(pb.z - pb.x, 0.0f) * fmaxf(pb.w - pb.y, 0.0f);
        float best = -1.0f;
        for (int g = 0; g < N; g++) {
            float4 g4 = gbS[g];
            float ga = fmaxf(g4.z - g4.x, 0.0f) * fmaxf(g4.w - g4.y, 0.0f);
            float xx1 = fmaxf(g4.x, pb.x), yy1 = fmaxf(g4.y, pb.y);
            float xx2 = fminf(g4.z, pb.z), yy2 = fminf(g4.w, pb.w);
            float inter = fmaxf(xx2 - xx1, 0.0f) * fmaxf(yy2 - yy1, 0.0f);
            float iou = inter / (((ga + pa) - inter) + EPSF);
            if (iou > best) { best = iou; gi = g; }
        }
        pos = 1;
    }
    out0[p] = (float)gi;
    out1[p] = pos ? (float)glS[gi] : 0.0f;
}

__global__ __launch_bounds__(256) void phaseC2(const float4* __restrict__ bboxg,
                                               const int* __restrict__ lbl,
                                               const float* __restrict__ out0,
                                               float* __restrict__ outcls,
                                               float* __restrict__ outbox, int P, int N) {
    __shared__ float gbb[256 * 4];
    __shared__ int glS[256];
    __shared__ int clsl[256];
    __shared__ int gil[256];
    int tid = threadIdx.x;
    if (tid < N) {
        float4 b = bboxg[tid];
        gbb[tid * 4 + 0] = b.x; gbb[tid * 4 + 1] = b.y;
        gbb[tid * 4 + 2] = b.z; gbb[tid * 4 + 3] = b.w;
        glS[tid] = lbl[tid];
    }
    __syncthreads();
    int p0 = blockIdx.x * 256;
    int nloc = P - p0; if (nloc > 256) nloc = 256;
    if (tid < nloc) {
        int gi = (int)out0[p0 + tid];
        gil[tid] = gi;
        clsl[tid] = glS[gi] - 1;
    }
    __syncthreads();
    for (int f = tid; f < nloc * NCLS; f += 256) {
        int pl = f / NCLS;
        int c  = f - pl * NCLS;
        outcls[(size_t)p0 * NCLS + f] = (c == clsl[pl]) ? 1.0f : 0.0f;
    }
    for (int f = tid; f < nloc * 4; f += 256) {
        int pl = f >> 2, k = f & 3;
        outbox[(size_t)p0 * 4 + f] = gbb[gil[pl] * 4 + k];
    }
}

extern "C" void kernel_launch(void* const* d_in, const int* in_sizes, int n_in,
                              void* d_out, int out_size, void* d_ws, size_t ws_size,
                              hipStream_t stream) {
    const float* cls_pred  = (const float*)d_in[0];
    const float* bbox_pred = (const float*)d_in[1];
    const int*   label_gt  = (const int*)d_in[2];
    const float* bbox_gt   = (const float*)d_in[3];
    int P = in_sizes[1] / 4;
    int N = in_sizes[3] / 4;

    float* out    = (float*)d_out;
    float* out0   = out;
    float* out1   = out + (size_t)P;
    float* outcls = out + (size_t)2 * P;      // one-hot region; clsT scratch pre-memset
    float* outbox = out + (size_t)82 * P;

    int tb = (P + 63) / 64;
    int pb = (P + 255) / 256;
    int seglen = (P + NSEG - 1) / NSEG;
    dim3 gridA1(NSEG, N);
    size_t candElems = (size_t)N * NSEG * TOPK;
    size_t needWs = ((size_t)P * 3 + 2 * candElems + 4) * sizeof(int);

    if (ws_size >= needWs) {
        // ws layout: count[P] | firstg[P] | parea[P] | cand (8B aligned)
        int*    count  = (int*)d_ws;
        int*    firstg = count + P;
        float*  parea  = (float*)(firstg + P);
        size_t  coff   = ((size_t)(3 * (size_t)P) * 4 + 7) & ~(size_t)7;
        float2* cand   = (float2*)((char*)d_ws + coff);

        prep<<<tb, 256, 0, stream>>>((const float4*)cls_pred, (const float4*)bbox_pred,
                                     outcls, parea, count, firstg, P);
        phaseA1<<<gridA1, 256, 0, stream>>>(outcls, (const float4*)bbox_pred, parea,
                                            (const float4*)bbox_gt, label_gt, cand, P, seglen);
        phaseA2<<<N, 128, 0, stream>>>(cand, count, firstg);
        hipMemsetAsync(outcls, 0, (size_t)NCLS * P * sizeof(float), stream);
        phaseC<<<pb, 256, 0, stream>>>((const float4*)bbox_pred, (const float4*)bbox_gt,
                                       label_gt, count, firstg, out0, out1, outcls,
                                       (float4*)outbox, P, N);
    } else {
        // fallback: alias scratch inside d_out (round-2 layout)
        int*    count  = (int*)outbox;
        int*    firstg = ((int*)outbox) + P;
        float2* cand   = (float2*)(((int*)outbox) + 2 * (size_t)P);
        float*  parea  = out0;

        prep<<<tb, 256, 0, stream>>>((const float4*)cls_pred, (const float4*)bbox_pred,
                                     outcls, parea, count, firstg, P);
        phaseA1<<<gridA1, 256, 0, stream>>>(outcls, (const float4*)bbox_pred, parea,
                                            (const float4*)bbox_gt, label_gt, cand, P, seglen);
        phaseA2<<<N, 128, 0, stream>>>(cand, count, firstg);
        phaseC1<<<pb, 256, 0, stream>>>((const float4*)bbox_pred, (const float4*)bbox_gt,
                                        label_gt, count, firstg, out0, out1, P, N);
        phaseC2<<<pb, 256, 0, stream>>>((const float4*)bbox_gt, label_gt, out0,
                                        outcls, outbox, P, N);
    }
}

// Round 4
// 259.549 us; speedup vs baseline: 1.6289x; 1.0779x over previous
//
#include <hip/hip_runtime.h>

#define TOPK 13
#define NCLS 80
#define EPSF 1e-9f
#define NSEG 32
#define GPB  8          // GTs per block (one per wave at selection time)
#define CAP2 832        // per-g candidate entries (=64*13 so buffer doubles as merge scratch)

// ---------------------------------------------------------------------------
// sortgt: stable sort GT indices by (class, g) -> gorder. One 256-thread block.
// Class-grouped GT tiles make the 8 crow streams per block dedup in L1/L2.
// ---------------------------------------------------------------------------
__global__ __launch_bounds__(256) void sortgt(const int* __restrict__ lbl,
                                              int* __restrict__ gorder, int N) {
    __shared__ int key[256];
    int t = threadIdx.x;
    key[t] = (t < N) ? ((lbl[t] << 8) | t) : 0x7FFFFFFF;
    __syncthreads();
    for (int k = 2; k <= 256; k <<= 1) {
        for (int j = k >> 1; j >= 1; j >>= 1) {
            int ixj = t ^ j;
            if (ixj > t) {
                int a = key[t], b = key[ixj];
                bool up = ((t & k) == 0);
                if (up ? (a > b) : (a < b)) { key[t] = b; key[ixj] = a; }
            }
            __syncthreads();
        }
    }
    if (t < N) gorder[t] = key[t] & 0xFF;
}

// ---------------------------------------------------------------------------
// prep: transpose cls_pred (P,80) -> clsT (80,P) (into one-hot out region);
// zero count / init firstg.
// ---------------------------------------------------------------------------
__global__ __launch_bounds__(256) void prep(const float4* __restrict__ cls4,
                                            float* __restrict__ clsT,
                                            int* __restrict__ count,
                                            int* __restrict__ firstg, int P) {
    __shared__ float tile[64 * 81];
    int p0 = blockIdx.x * 64;
    int valid = P - p0; if (valid > 64) valid = 64;
    int t = threadIdx.x;
    int limq = valid * 20;
    for (int f = t; f < 64 * 20; f += 256) {
        int pl = f / 20, cq = f - pl * 20;
        float4 v = (f < limq) ? cls4[(size_t)p0 * 20 + f] : make_float4(0, 0, 0, 0);
        tile[pl * 81 + 4 * cq + 0] = v.x;
        tile[pl * 81 + 4 * cq + 1] = v.y;
        tile[pl * 81 + 4 * cq + 2] = v.z;
        tile[pl * 81 + 4 * cq + 3] = v.w;
    }
    if (t < 64 && t < valid) { count[p0 + t] = 0; firstg[p0 + t] = 0x7FFFFFFF; }
    __syncthreads();
    for (int f = t; f < 80 * 16; f += 256) {
        int c = f >> 4, j4 = f & 15;
        int j = 4 * j4;
        if (j < valid) {
            float4 o;
            o.x = tile[(j + 0) * 81 + c];
            o.y = tile[(j + 1) * 81 + c];
            o.z = tile[(j + 2) * 81 + c];
            o.w = tile[(j + 3) * 81 + c];
            *(float4*)&clsT[(size_t)c * P + p0 + j] = o;
        }
    }
}

// ---------------------------------------------------------------------------
// phaseA1: grid (NSEG, ceil(N/8)), 512 threads. One bbox load serves 8 GTs.
// Positives (m>0) + forced first-16 elements append to per-g LDS buffers via
// per-lane atomics. Then wave w selects exact top-13 of g=w ((val desc,
// idx asc) ties) via per-lane lists + in-wave LDS tree merge.
// ---------------------------------------------------------------------------
__global__ __launch_bounds__(512) void phaseA1(const float* __restrict__ clsT,
                                               const float4* __restrict__ bboxp,
                                               const float4* __restrict__ bboxg,
                                               const int* __restrict__ lbl,
                                               const int* __restrict__ gorder,
                                               float2* __restrict__ cand,
                                               int P, int N, int seglen) {
#pragma clang fp contract(off)
    const int s = blockIdx.x, tile = blockIdx.y, t = threadIdx.x;
    const int wv = t >> 6, lane = t & 63;
    const int pstart = s * seglen;
    int pend = pstart + seglen; if (pend > P) pend = P;

    __shared__ float2 buf[GPB][CAP2];
    __shared__ int ctr[GPB];

    float4 gb[GPB]; float ga[GPB]; const float* crow[GPB]; int gid[GPB]; bool gv[GPB];
#pragma unroll
    for (int j = 0; j < GPB; j++) {
        int gi8 = tile * GPB + j;
        gv[j] = gi8 < N;
        gid[j] = gv[j] ? gorder[gi8] : 0;
        gb[j] = bboxg[gid[j]];
        int c = lbl[gid[j]] - 1; if (c < 0) c = 0; if (c >= NCLS) c = NCLS - 1;
        crow[j] = clsT + (size_t)c * P;
        ga[j] = fmaxf(gb[j].z - gb[j].x, 0.0f) * fmaxf(gb[j].w - gb[j].y, 0.0f);
    }
    if (t < GPB) ctr[t] = 0;
    __syncthreads();

    bool first = true;
    for (int p = pstart + t; p < pend; p += 512) {
        float4 pb = bboxp[p];
        float pa = fmaxf(pb.z - pb.x, 0.0f) * fmaxf(pb.w - pb.y, 0.0f);
        bool force = first && (t < 16);
        first = false;
        float sc[GPB];
#pragma unroll
        for (int j = 0; j < GPB; j++) sc[j] = crow[j][p];
#pragma unroll
        for (int j = 0; j < GPB; j++) {
            float xx1 = fmaxf(gb[j].x, pb.x), yy1 = fmaxf(gb[j].y, pb.y);
            float xx2 = fminf(gb[j].z, pb.z), yy2 = fminf(gb[j].w, pb.w);
            float inter = fmaxf(xx2 - xx1, 0.0f) * fmaxf(yy2 - yy1, 0.0f);
            float iou = inter / (((ga[j] + pa) - inter) + EPSF);
            float i2 = iou * iou;
            float m = sc[j] * ((i2 * i2) * i2);
            bool want = gv[j] && ((m > 0.0f) || force);
            if (want) {
                int slot = atomicAdd(&ctr[j], 1);
                if (slot < CAP2) buf[j][slot] = make_float2(m, __int_as_float(p));
            }
        }
    }
    __syncthreads();

    // --- wave wv owns g-slot j = wv ---
    const int j = wv;
    const int total = ctr[j];
    float v[TOPK]; int id[TOPK];
#pragma unroll
    for (int k = 0; k < TOPK; k++) { v[k] = -1.0f; id[k] = 0x7FFFFFFF; }

    auto ins = [&](float m, int p) {
        bool b12 = (m > v[TOPK - 1]) || (m == v[TOPK - 1] && p < id[TOPK - 1]);
        if (b12) {
#pragma unroll
            for (int k = TOPK - 1; k >= 1; k--) {
                bool a = (m > v[k - 1]) || (m == v[k - 1] && p < id[k - 1]);
                bool b = (m > v[k]) || (m == v[k] && p < id[k]);
                float nv = a ? v[k - 1] : (b ? m : v[k]);
                int   ni = a ? id[k - 1] : (b ? p : id[k]);
                v[k] = nv; id[k] = ni;
            }
            bool a0 = (m > v[0]) || (m == v[0] && p < id[0]);
            if (a0) { v[0] = m; id[0] = p; }
        }
    };

    if (total <= CAP2) {
        for (int e = lane; e < total; e += 64) {
            float2 E = buf[j][e];
            ins(E.x, __float_as_int(E.y));
        }
    } else {
        // overflow: exact rescan of the whole segment for this g (cold path)
        for (int p = pstart + lane; p < pend; p += 64) {
            float4 pb = bboxp[p];
            float pa = fmaxf(pb.z - pb.x, 0.0f) * fmaxf(pb.w - pb.y, 0.0f);
            float xx1 = fmaxf(gb[j].x, pb.x), yy1 = fmaxf(gb[j].y, pb.y);
            float xx2 = fminf(gb[j].z, pb.z), yy2 = fminf(gb[j].w, pb.w);
            float inter = fmaxf(xx2 - xx1, 0.0f) * fmaxf(yy2 - yy1, 0.0f);
            float iou = inter / (((ga[j] + pa) - inter) + EPSF);
            float i2 = iou * iou;
            float m = crow[j][p] * ((i2 * i2) * i2);
            ins(m, p);
        }
    }
    __syncthreads();   // buffer reads complete before reuse as merge scratch

    float2* wl = buf[j];
#pragma unroll
    for (int k = 0; k < TOPK; k++)
        wl[lane * TOPK + k] = make_float2(v[k], __int_as_float(id[k]));
    __syncthreads();
    for (int str = 32; str >= 1; str >>= 1) {
        if (lane < str) {
            float2 merged[TOPK];
            int a = 0, b = 0;
            const int ba = lane * TOPK, bb = (lane + str) * TOPK;
#pragma unroll
            for (int k = 0; k < TOPK; k++) {
                float2 fa = wl[ba + a], fb = wl[bb + b];
                int ia = __float_as_int(fa.y), ib = __float_as_int(fb.y);
                bool takeA = (fa.x > fb.x) || (fa.x == fb.x && ia < ib);
                merged[k] = takeA ? fa : fb;
                a += takeA; b += !takeA;
            }
#pragma unroll
            for (int k = 0; k < TOPK; k++) wl[ba + k] = merged[k];
        }
        __syncthreads();
    }
    if (lane < TOPK && gv[j])
        cand[((size_t)gid[j] * NSEG + s) * TOPK + lane] = wl[lane];
}

// ---------------------------------------------------------------------------
// phaseA2: per GT merge NSEG*13=416 candidates -> exact global top-13 via a
// 512-element bitonic sort, then scatter count/firstg atomics if max > eps.
// ---------------------------------------------------------------------------
__global__ __launch_bounds__(512) void phaseA2(const float2* __restrict__ cand,
                                               int* __restrict__ count,
                                               int* __restrict__ firstg) {
    const int g = blockIdx.x;
    const int t = threadIdx.x;
    const int M = NSEG * TOPK;  // 416
    __shared__ float cv[512];
    __shared__ int   ci[512];
    if (t < M) {
        float2 e = cand[(size_t)g * M + t];
        cv[t] = e.x; ci[t] = __float_as_int(e.y);
    } else {
        cv[t] = -1.0f; ci[t] = 0x7FFFFFFF;
    }
    __syncthreads();
    for (int k = 2; k <= 512; k <<= 1) {
        for (int j = k >> 1; j >= 1; j >>= 1) {
            int ixj = t ^ j;
            if (ixj > t) {
                float va = cv[t], vb = cv[ixj];
                int   ia = ci[t], ib = ci[ixj];
                bool aBeforeB = (va > vb) || (va == vb && ia < ib);
                bool dirFwd = ((t & k) == 0);
                bool doswap = dirFwd ? !aBeforeB : aBeforeB;
                if (doswap) { cv[t] = vb; ci[t] = ib; cv[ixj] = va; ci[ixj] = ia; }
            }
            __syncthreads();
        }
    }
    if (t < TOPK && cv[0] > EPSF) {
        int pi = ci[t];
        atomicAdd(&count[pi], 1);
        atomicMin(&firstg[pi], g);
    }
}

// ---------------------------------------------------------------------------
// phaseCF (ws path): fused resolve + all outputs, dense coalesced writes.
// ---------------------------------------------------------------------------
__global__ __launch_bounds__(256) void phaseCF(const float4* __restrict__ bboxp,
                                               const float4* __restrict__ bboxg,
                                               const int* __restrict__ lbl,
                                               const int* __restrict__ count,
                                               const int* __restrict__ firstg,
                                               float* __restrict__ out0,
                                               float* __restrict__ out1,
                                               float4* __restrict__ outcls4,
                                               float4* __restrict__ outbox4, int P, int N) {
#pragma clang fp contract(off)
    __shared__ float4 gbS[256];
    __shared__ int glS[256];
    __shared__ int gil[256];
    __shared__ int clsl[256];
    int t = threadIdx.x;
    if (t < N) { gbS[t] = bboxg[t]; glS[t] = lbl[t]; }
    __syncthreads();
    int p0 = blockIdx.x * 256;
    int nloc = P - p0; if (nloc > 256) nloc = 256;
    if (t < nloc) {
        int p = p0 + t;
        int cnt = count[p];
        int gi = 0, pos = 0;
        if (cnt == 1) { gi = firstg[p]; pos = 1; }
        else if (cnt > 1) {
            float4 pb = bboxp[p];
            float pa = fmaxf(pb.z - pb.x, 0.0f) * fmaxf(pb.w - pb.y, 0.0f);
            float best = -1.0f;
            for (int g = 0; g < N; g++) {
                float4 g4 = gbS[g];
                float gar = fmaxf(g4.z - g4.x, 0.0f) * fmaxf(g4.w - g4.y, 0.0f);
                float xx1 = fmaxf(g4.x, pb.x), yy1 = fmaxf(g4.y, pb.y);
                float xx2 = fminf(g4.z, pb.z), yy2 = fminf(g4.w, pb.w);
                float inter = fmaxf(xx2 - xx1, 0.0f) * fmaxf(yy2 - yy1, 0.0f);
                float iou = inter / (((gar + pa) - inter) + EPSF);
                if (iou > best) { best = iou; gi = g; }   // strict > == first-max
            }
            pos = 1;
        }
        out0[p] = (float)gi;
        out1[p] = pos ? (float)glS[gi] : 0.0f;
        gil[t] = gi;
        clsl[t] = glS[gi] - 1;
        outbox4[p] = gbS[gi];
    }
    __syncthreads();
    for (int f = t; f < nloc * 20; f += 256) {
        int pl = f / 20, q = f - pl * 20;
        int cl = clsl[pl], c0 = q * 4;
        float4 vv = make_float4(c0 == cl ? 1.0f : 0.0f, c0 + 1 == cl ? 1.0f : 0.0f,
                                c0 + 2 == cl ? 1.0f : 0.0f, c0 + 3 == cl ? 1.0f : 0.0f);
        outcls4[(size_t)p0 * 20 + f] = vv;
    }
}

// ---------------------------------------------------------------------------
// Fallback path (small ws): scratch aliases the bbox-output region, so split
// resolve (C1) and dense writes (C2) into separate launches.
// ---------------------------------------------------------------------------
__global__ __launch_bounds__(256) void phaseC1(const float4* __restrict__ bboxp,
                                               const float4* __restrict__ bboxg,
                                               const int* __restrict__ lbl,
                                               const int* __restrict__ count,
                                               const int* __restrict__ firstg,
                                               float* __restrict__ out0,
                                               float* __restrict__ out1, int P, int N) {
#pragma clang fp contract(off)
    __shared__ float4 gbS[256];
    __shared__ int glS[256];
    if (threadIdx.x < (unsigned)N) {
        gbS[threadIdx.x] = bboxg[threadIdx.x];
        glS[threadIdx.x] = lbl[threadIdx.x];
    }
    __syncthreads();
    int p = blockIdx.x * 256 + threadIdx.x;
    if (p >= P) return;
    int cnt = count[p];
    int gi = 0, pos = 0;
    if (cnt == 1) { gi = firstg[p]; pos = 1; }
    else if (cnt > 1) {
        float4 pb = bboxp[p];
        float pa = fmaxf(pb.z - pb.x, 0.0f) * fmaxf(pb.w - pb.y, 0.0f);
        float best = -1.0f;
        for (int g = 0; g < N; g++) {
            float4 g4 = gbS[g];
            float gar = fmaxf(g4.z - g4.x, 0.0f) * fmaxf(g4.w - g4.y, 0.0f);
            float xx1 = fmaxf(g4.x, pb.x), yy1 = fmaxf(g4.y, pb.y);
            float xx2 = fminf(g4.z, pb.z), yy2 = fminf(g4.w, pb.w);
            float inter = fmaxf(xx2 - xx1, 0.0f) * fmaxf(yy2 - yy1, 0.0f);
            float iou = inter / (((gar + pa) - inter) + EPSF);
            if (iou > best) { best = iou; gi = g; }
        }
        pos = 1;
    }
    out0[p] = (float)gi;
    out1[p] = pos ? (float)glS[gi] : 0.0f;
}

__global__ __launch_bounds__(256) void phaseC2(const float4* __restrict__ bboxg,
                                               const int* __restrict__ lbl,
                                               const float* __restrict__ out0,
                                               float* __restrict__ outcls,
                                               float* __restrict__ outbox, int P, int N) {
    __shared__ float gbb[256 * 4];
    __shared__ int glS[256];
    __shared__ int clsl[256];
    __shared__ int gil[256];
    int tid = threadIdx.x;
    if (tid < N) {
        float4 b = bboxg[tid];
        gbb[tid * 4 + 0] = b.x; gbb[tid * 4 + 1] = b.y;
        gbb[tid * 4 + 2] = b.z; gbb[tid * 4 + 3] = b.w;
        glS[tid] = lbl[tid];
    }
    __syncthreads();
    int p0 = blockIdx.x * 256;
    int nloc = P - p0; if (nloc > 256) nloc = 256;
    if (tid < nloc) {
        int gi = (int)out0[p0 + tid];
        gil[tid] = gi;
        clsl[tid] = glS[gi] - 1;
    }
    __syncthreads();
    for (int f = tid; f < nloc * NCLS; f += 256) {
        int pl = f / NCLS;
        int c  = f - pl * NCLS;
        outcls[(size_t)p0 * NCLS + f] = (c == clsl[pl]) ? 1.0f : 0.0f;
    }
    for (int f = tid; f < nloc * 4; f += 256) {
        int pl = f >> 2, k = f & 3;
        outbox[(size_t)p0 * 4 + f] = gbb[gil[pl] * 4 + k];
    }
}

extern "C" void kernel_launch(void* const* d_in, const int* in_sizes, int n_in,
                              void* d_out, int out_size, void* d_ws, size_t ws_size,
                              hipStream_t stream) {
    const float* cls_pred  = (const float*)d_in[0];
    const float* bbox_pred = (const float*)d_in[1];
    const int*   label_gt  = (const int*)d_in[2];
    const float* bbox_gt   = (const float*)d_in[3];
    int P = in_sizes[1] / 4;
    int N = in_sizes[3] / 4;

    float* out    = (float*)d_out;
    float* out0   = out;
    float* out1   = out + (size_t)P;
    float* outcls = out + (size_t)2 * P;      // one-hot region; clsT scratch first
    float* outbox = out + (size_t)82 * P;

    int tb = (P + 63) / 64;
    int pb = (P + 255) / 256;
    int seglen = (P + NSEG - 1) / NSEG;
    int gtiles = (N + GPB - 1) / GPB;
    dim3 gridA1(NSEG, gtiles);
    size_t candBytes = (size_t)N * NSEG * TOPK * sizeof(float2);
    size_t needWs = (size_t)P * 8 + candBytes + (size_t)N * 4 + 64;

    if (ws_size >= needWs) {
        // ws: count[P] | firstg[P] | cand | gorder[N]
        int*    count  = (int*)d_ws;
        int*    firstg = count + P;
        float2* cand   = (float2*)(firstg + P);
        int*    gorder = (int*)((char*)cand + candBytes);

        sortgt<<<1, 256, 0, stream>>>(label_gt, gorder, N);
        prep<<<tb, 256, 0, stream>>>((const float4*)cls_pred, outcls, count, firstg, P);
        phaseA1<<<gridA1, 512, 0, stream>>>(outcls, (const float4*)bbox_pred,
                                            (const float4*)bbox_gt, label_gt, gorder,
                                            cand, P, N, seglen);
        phaseA2<<<N, 512, 0, stream>>>(cand, count, firstg);
        phaseCF<<<pb, 256, 0, stream>>>((const float4*)bbox_pred, (const float4*)bbox_gt,
                                        label_gt, count, firstg, out0, out1,
                                        (float4*)outcls, (float4*)outbox, P, N);
    } else {
        // fallback: scratch inside outbox region (4P floats = P*16 bytes)
        int*    count  = (int*)outbox;
        int*    firstg = ((int*)outbox) + P;
        float2* cand   = (float2*)(((int*)outbox) + 2 * (size_t)P);
        int*    gorder = (int*)((char*)cand + candBytes);

        sortgt<<<1, 256, 0, stream>>>(label_gt, gorder, N);
        prep<<<tb, 256, 0, stream>>>((const float4*)cls_pred, outcls, count, firstg, P);
        phaseA1<<<gridA1, 512, 0, stream>>>(outcls, (const float4*)bbox_pred,
                                            (const float4*)bbox_gt, label_gt, gorder,
                                            cand, P, N, seglen);
        phaseA2<<<N, 512, 0, stream>>>(cand, count, firstg);
        phaseC1<<<pb, 256, 0, stream>>>((const float4*)bbox_pred, (const float4*)bbox_gt,
                                        label_gt, count, firstg, out0, out1, P, N);
        phaseC2<<<pb, 256, 0, stream>>>((const float4*)bbox_gt, label_gt, out0,
                                        outcls, outbox, P, N);
    }
}

// Round 5
// 232.943 us; speedup vs baseline: 1.8149x; 1.1142x over previous
//
#include <hip/hip_runtime.h>

#define TOPK 13
#define NCLS 80
#define EPSF 1e-9f
#define NSEG 32
#define GPB  8          // GTs per block (one per wave at selection time)
#define CAP2 832        // per-g candidate entries (=64*13 so buffer doubles as merge scratch)

// ---------------------------------------------------------------------------
// sortgt: stable sort GT indices by (class, g) -> gorder. One 256-thread block.
// Class-grouped GT tiles make the 8 crow streams per block dedup in L1/L2.
// ---------------------------------------------------------------------------
__global__ __launch_bounds__(256) void sortgt(const int* __restrict__ lbl,
                                              int* __restrict__ gorder, int N) {
    __shared__ int key[256];
    int t = threadIdx.x;
    key[t] = (t < N) ? ((lbl[t] << 8) | t) : 0x7FFFFFFF;
    __syncthreads();
    for (int k = 2; k <= 256; k <<= 1) {
        for (int j = k >> 1; j >= 1; j >>= 1) {
            int ixj = t ^ j;
            if (ixj > t) {
                int a = key[t], b = key[ixj];
                bool up = ((t & k) == 0);
                if (up ? (a > b) : (a < b)) { key[t] = b; key[ixj] = a; }
            }
            __syncthreads();
        }
    }
    if (t < N) gorder[t] = key[t] & 0xFF;
}

// ---------------------------------------------------------------------------
// prep: transpose cls_pred (P,80) -> clsT (80,P) (into one-hot out region);
// zero count / init firstg.
// ---------------------------------------------------------------------------
__global__ __launch_bounds__(256) void prep(const float4* __restrict__ cls4,
                                            float* __restrict__ clsT,
                                            int* __restrict__ count,
                                            int* __restrict__ firstg, int P) {
    __shared__ float tile[64 * 81];
    int p0 = blockIdx.x * 64;
    int valid = P - p0; if (valid > 64) valid = 64;
    int t = threadIdx.x;
    int limq = valid * 20;
    for (int f = t; f < 64 * 20; f += 256) {
        int pl = f / 20, cq = f - pl * 20;
        float4 v = (f < limq) ? cls4[(size_t)p0 * 20 + f] : make_float4(0, 0, 0, 0);
        tile[pl * 81 + 4 * cq + 0] = v.x;
        tile[pl * 81 + 4 * cq + 1] = v.y;
        tile[pl * 81 + 4 * cq + 2] = v.z;
        tile[pl * 81 + 4 * cq + 3] = v.w;
    }
    if (t < 64 && t < valid) { count[p0 + t] = 0; firstg[p0 + t] = 0x7FFFFFFF; }
    __syncthreads();
    for (int f = t; f < 80 * 16; f += 256) {
        int c = f >> 4, j4 = f & 15;
        int j = 4 * j4;
        if (j < valid) {
            float4 o;
            o.x = tile[(j + 0) * 81 + c];
            o.y = tile[(j + 1) * 81 + c];
            o.z = tile[(j + 2) * 81 + c];
            o.w = tile[(j + 3) * 81 + c];
            *(float4*)&clsT[(size_t)c * P + p0 + j] = o;
        }
    }
}

// ---------------------------------------------------------------------------
// phaseA1: grid (NSEG, ceil(N/8)), 512 threads. One bbox load serves 8 GTs.
// All per-thread GT state indexed ONLY by compile-time constants (stays in
// VGPRs; launch_bounds(512,4) caps at 128 VGPRs = 4 waves/EU, matching the
// 2-blocks/CU LDS limit). Overflow rescan reloads GT data from global.
// ---------------------------------------------------------------------------
__global__ __launch_bounds__(512, 4) void phaseA1(const float* __restrict__ clsT,
                                                  const float4* __restrict__ bboxp,
                                                  const float4* __restrict__ bboxg,
                                                  const int* __restrict__ lbl,
                                                  const int* __restrict__ gorder,
                                                  float2* __restrict__ cand,
                                                  int P, int N, int seglen) {
#pragma clang fp contract(off)
    const int s = blockIdx.x, tile = blockIdx.y, t = threadIdx.x;
    const int wv = t >> 6, lane = t & 63;
    const int pstart = s * seglen;
    int pend = pstart + seglen; if (pend > P) pend = P;

    __shared__ float2 buf[GPB][CAP2];
    __shared__ int ctr[GPB];

    float4 gb[GPB]; float ga[GPB]; int coff[GPB];
#pragma unroll
    for (int j = 0; j < GPB; j++) {
        int gi8 = tile * GPB + j;
        int gj = (gi8 < N) ? gorder[gi8] : -1;
        if (gj >= 0) {
            gb[j] = bboxg[gj];
            int c = lbl[gj] - 1;
            coff[j] = c * P;
        } else {
            gb[j] = make_float4(0.0f, 0.0f, 0.0f, 0.0f);  // empty box -> iou 0 -> m 0
            coff[j] = 0;
        }
        ga[j] = fmaxf(gb[j].z - gb[j].x, 0.0f) * fmaxf(gb[j].w - gb[j].y, 0.0f);
    }
    const bool myValid = (tile * GPB + wv) < N;
    if (t < GPB) ctr[t] = 0;
    __syncthreads();

    bool first = true;
    for (int p = pstart + t; p < pend; p += 512) {
        float4 pb = bboxp[p];
        float pa = fmaxf(pb.z - pb.x, 0.0f) * fmaxf(pb.w - pb.y, 0.0f);
        bool force = first && (t < 16);
        first = false;
        float sc[GPB];
#pragma unroll
        for (int j = 0; j < GPB; j++) sc[j] = clsT[coff[j] + p];
#pragma unroll
        for (int j = 0; j < GPB; j++) {
            float xx1 = fmaxf(gb[j].x, pb.x), yy1 = fmaxf(gb[j].y, pb.y);
            float xx2 = fminf(gb[j].z, pb.z), yy2 = fminf(gb[j].w, pb.w);
            float inter = fmaxf(xx2 - xx1, 0.0f) * fmaxf(yy2 - yy1, 0.0f);
            float iou = inter / (((ga[j] + pa) - inter) + EPSF);
            float i2 = iou * iou;
            float m = sc[j] * ((i2 * i2) * i2);
            bool want = (m > 0.0f) || force;
            if (want) {
                int slot = atomicAdd(&ctr[j], 1);
                if (slot < CAP2) buf[j][slot] = make_float2(m, __int_as_float(p));
            }
        }
    }
    __syncthreads();

    // --- wave wv owns g-slot wv; NO runtime indexing of register arrays ---
    const int total = ctr[wv];
    float v[TOPK]; int id[TOPK];
#pragma unroll
    for (int k = 0; k < TOPK; k++) { v[k] = -1.0f; id[k] = 0x7FFFFFFF; }

    auto ins = [&](float m, int p) {
        bool b12 = (m > v[TOPK - 1]) || (m == v[TOPK - 1] && p < id[TOPK - 1]);
        if (b12) {
#pragma unroll
            for (int k = TOPK - 1; k >= 1; k--) {
                bool a = (m > v[k - 1]) || (m == v[k - 1] && p < id[k - 1]);
                bool b = (m > v[k]) || (m == v[k] && p < id[k]);
                float nv = a ? v[k - 1] : (b ? m : v[k]);
                int   ni = a ? id[k - 1] : (b ? p : id[k]);
                v[k] = nv; id[k] = ni;
            }
            bool a0 = (m > v[0]) || (m == v[0] && p < id[0]);
            if (a0) { v[0] = m; id[0] = p; }
        }
    };

    if (total <= CAP2) {
        for (int e = lane; e < total; e += 64) {
            float2 E = buf[wv][e];
            ins(E.x, __float_as_int(E.y));
        }
    } else if (myValid) {
        // overflow: exact rescan, reloading GT data from GLOBAL (cold path;
        // avoids runtime-indexing the register arrays -> no scratch alloc)
        int gj = gorder[tile * GPB + wv];
        float4 gbw = bboxg[gj];
        float gaw = fmaxf(gbw.z - gbw.x, 0.0f) * fmaxf(gbw.w - gbw.y, 0.0f);
        const float* crow = clsT + (size_t)(lbl[gj] - 1) * P;
        for (int p = pstart + lane; p < pend; p += 64) {
            float4 pb = bboxp[p];
            float pa = fmaxf(pb.z - pb.x, 0.0f) * fmaxf(pb.w - pb.y, 0.0f);
            float xx1 = fmaxf(gbw.x, pb.x), yy1 = fmaxf(gbw.y, pb.y);
            float xx2 = fminf(gbw.z, pb.z), yy2 = fminf(gbw.w, pb.w);
            float inter = fmaxf(xx2 - xx1, 0.0f) * fmaxf(yy2 - yy1, 0.0f);
            float iou = inter / (((gaw + pa) - inter) + EPSF);
            float i2 = iou * iou;
            float m = crow[p] * ((i2 * i2) * i2);
            ins(m, p);
        }
    }
    __syncthreads();   // buffer reads complete before reuse as merge scratch

    float2* wl = buf[wv];
#pragma unroll
    for (int k = 0; k < TOPK; k++)
        wl[lane * TOPK + k] = make_float2(v[k], __int_as_float(id[k]));
    __syncthreads();
    for (int str = 32; str >= 1; str >>= 1) {
        if (lane < str) {
            float2 merged[TOPK];
            int a = 0, b = 0;
            const int ba = lane * TOPK, bb = (lane + str) * TOPK;
#pragma unroll
            for (int k = 0; k < TOPK; k++) {
                float2 fa = wl[ba + a], fb = wl[bb + b];
                int ia = __float_as_int(fa.y), ib = __float_as_int(fb.y);
                bool takeA = (fa.x > fb.x) || (fa.x == fb.x && ia < ib);
                merged[k] = takeA ? fa : fb;
                a += takeA; b += !takeA;
            }
#pragma unroll
            for (int k = 0; k < TOPK; k++) wl[ba + k] = merged[k];
        }
        __syncthreads();
    }
    if (lane < TOPK && myValid) {
        int gj = gorder[tile * GPB + wv];
        cand[((size_t)gj * NSEG + s) * TOPK + lane] = wl[lane];
    }
}

// ---------------------------------------------------------------------------
// phaseA2: per GT merge NSEG*13=416 candidates -> exact global top-13 via a
// 512-element bitonic sort, then scatter count/firstg atomics if max > eps.
// ---------------------------------------------------------------------------
__global__ __launch_bounds__(512) void phaseA2(const float2* __restrict__ cand,
                                               int* __restrict__ count,
                                               int* __restrict__ firstg) {
    const int g = blockIdx.x;
    const int t = threadIdx.x;
    const int M = NSEG * TOPK;  // 416
    __shared__ float cv[512];
    __shared__ int   ci[512];
    if (t < M) {
        float2 e = cand[(size_t)g * M + t];
        cv[t] = e.x; ci[t] = __float_as_int(e.y);
    } else {
        cv[t] = -1.0f; ci[t] = 0x7FFFFFFF;
    }
    __syncthreads();
    for (int k = 2; k <= 512; k <<= 1) {
        for (int j = k >> 1; j >= 1; j >>= 1) {
            int ixj = t ^ j;
            if (ixj > t) {
                float va = cv[t], vb = cv[ixj];
                int   ia = ci[t], ib = ci[ixj];
                bool aBeforeB = (va > vb) || (va == vb && ia < ib);
                bool dirFwd = ((t & k) == 0);
                bool doswap = dirFwd ? !aBeforeB : aBeforeB;
                if (doswap) { cv[t] = vb; ci[t] = ib; cv[ixj] = va; ci[ixj] = ia; }
            }
            __syncthreads();
        }
    }
    if (t < TOPK && cv[0] > EPSF) {
        int pi = ci[t];
        atomicAdd(&count[pi], 1);
        atomicMin(&firstg[pi], g);
    }
}

// ---------------------------------------------------------------------------
// phaseCF (ws path): fused resolve + all outputs, dense coalesced writes.
// ---------------------------------------------------------------------------
__global__ __launch_bounds__(256) void phaseCF(const float4* __restrict__ bboxp,
                                               const float4* __restrict__ bboxg,
                                               const int* __restrict__ lbl,
                                               const int* __restrict__ count,
                                               const int* __restrict__ firstg,
                                               float* __restrict__ out0,
                                               float* __restrict__ out1,
                                               float4* __restrict__ outcls4,
                                               float4* __restrict__ outbox4, int P, int N) {
#pragma clang fp contract(off)
    __shared__ float4 gbS[256];
    __shared__ int glS[256];
    __shared__ int gil[256];
    __shared__ int clsl[256];
    int t = threadIdx.x;
    if (t < N) { gbS[t] = bboxg[t]; glS[t] = lbl[t]; }
    __syncthreads();
    int p0 = blockIdx.x * 256;
    int nloc = P - p0; if (nloc > 256) nloc = 256;
    if (t < nloc) {
        int p = p0 + t;
        int cnt = count[p];
        int gi = 0, pos = 0;
        if (cnt == 1) { gi = firstg[p]; pos = 1; }
        else if (cnt > 1) {
            float4 pb = bboxp[p];
            float pa = fmaxf(pb.z - pb.x, 0.0f) * fmaxf(pb.w - pb.y, 0.0f);
            float best = -1.0f;
            for (int g = 0; g < N; g++) {
                float4 g4 = gbS[g];
                float gar = fmaxf(g4.z - g4.x, 0.0f) * fmaxf(g4.w - g4.y, 0.0f);
                float xx1 = fmaxf(g4.x, pb.x), yy1 = fmaxf(g4.y, pb.y);
                float xx2 = fminf(g4.z, pb.z), yy2 = fminf(g4.w, pb.w);
                float inter = fmaxf(xx2 - xx1, 0.0f) * fmaxf(yy2 - yy1, 0.0f);
                float iou = inter / (((gar + pa) - inter) + EPSF);
                if (iou > best) { best = iou; gi = g; }   // strict > == first-max
            }
            pos = 1;
        }
        out0[p] = (float)gi;
        out1[p] = pos ? (float)glS[gi] : 0.0f;
        gil[t] = gi;
        clsl[t] = glS[gi] - 1;
        outbox4[p] = gbS[gi];
    }
    __syncthreads();
    for (int f = t; f < nloc * 20; f += 256) {
        int pl = f / 20, q = f - pl * 20;
        int cl = clsl[pl], c0 = q * 4;
        float4 vv = make_float4(c0 == cl ? 1.0f : 0.0f, c0 + 1 == cl ? 1.0f : 0.0f,
                                c0 + 2 == cl ? 1.0f : 0.0f, c0 + 3 == cl ? 1.0f : 0.0f);
        outcls4[(size_t)p0 * 20 + f] = vv;
    }
}

// ---------------------------------------------------------------------------
// Fallback path (small ws): scratch aliases the bbox-output region, so split
// resolve (C1) and dense writes (C2) into separate launches.
// ---------------------------------------------------------------------------
__global__ __launch_bounds__(256) void phaseC1(const float4* __restrict__ bboxp,
                                               const float4* __restrict__ bboxg,
                                               const int* __restrict__ lbl,
                                               const int* __restrict__ count,
                                               const int* __restrict__ firstg,
                                               float* __restrict__ out0,
                                               float* __restrict__ out1, int P, int N) {
#pragma clang fp contract(off)
    __shared__ float4 gbS[256];
    __shared__ int glS[256];
    if (threadIdx.x < (unsigned)N) {
        gbS[threadIdx.x] = bboxg[threadIdx.x];
        glS[threadIdx.x] = lbl[threadIdx.x];
    }
    __syncthreads();
    int p = blockIdx.x * 256 + threadIdx.x;
    if (p >= P) return;
    int cnt = count[p];
    int gi = 0, pos = 0;
    if (cnt == 1) { gi = firstg[p]; pos = 1; }
    else if (cnt > 1) {
        float4 pb = bboxp[p];
        float pa = fmaxf(pb.z - pb.x, 0.0f) * fmaxf(pb.w - pb.y, 0.0f);
        float best = -1.0f;
        for (int g = 0; g < N; g++) {
            float4 g4 = gbS[g];
            float gar = fmaxf(g4.z - g4.x, 0.0f) * fmaxf(g4.w - g4.y, 0.0f);
            float xx1 = fmaxf(g4.x, pb.x), yy1 = fmaxf(g4.y, pb.y);
            float xx2 = fminf(g4.z, pb.z), yy2 = fminf(g4.w, pb.w);
            float inter = fmaxf(xx2 - xx1, 0.0f) * fmaxf(yy2 - yy1, 0.0f);
            float iou = inter / (((gar + pa) - inter) + EPSF);
            if (iou > best) { best = iou; gi = g; }
        }
        pos = 1;
    }
    out0[p] = (float)gi;
    out1[p] = pos ? (float)glS[gi] : 0.0f;
}

__global__ __launch_bounds__(256) void phaseC2(const float4* __restrict__ bboxg,
                                               const int* __restrict__ lbl,
                                               const float* __restrict__ out0,
                                               float* __restrict__ outcls,
                                               float* __restrict__ outbox, int P, int N) {
    __shared__ float gbb[256 * 4];
    __shared__ int glS[256];
    __shared__ int clsl[256];
    __shared__ int gil[256];
    int tid = threadIdx.x;
    if (tid < N) {
        float4 b = bboxg[tid];
        gbb[tid * 4 + 0] = b.x; gbb[tid * 4 + 1] = b.y;
        gbb[tid * 4 + 2] = b.z; gbb[tid * 4 + 3] = b.w;
        glS[tid] = lbl[tid];
    }
    __syncthreads();
    int p0 = blockIdx.x * 256;
    int nloc = P - p0; if (nloc > 256) nloc = 256;
    if (tid < nloc) {
        int gi = (int)out0[p0 + tid];
        gil[tid] = gi;
        clsl[tid] = glS[gi] - 1;
    }
    __syncthreads();
    for (int f = tid; f < nloc * NCLS; f += 256) {
        int pl = f / NCLS;
        int c  = f - pl * NCLS;
        outcls[(size_t)p0 * NCLS + f] = (c == clsl[pl]) ? 1.0f : 0.0f;
    }
    for (int f = tid; f < nloc * 4; f += 256) {
        int pl = f >> 2, k = f & 3;
        outbox[(size_t)p0 * 4 + f] = gbb[gil[pl] * 4 + k];
    }
}

extern "C" void kernel_launch(void* const* d_in, const int* in_sizes, int n_in,
                              void* d_out, int out_size, void* d_ws, size_t ws_size,
                              hipStream_t stream) {
    const float* cls_pred  = (const float*)d_in[0];
    const float* bbox_pred = (const float*)d_in[1];
    const int*   label_gt  = (const int*)d_in[2];
    const float* bbox_gt   = (const float*)d_in[3];
    int P = in_sizes[1] / 4;
    int N = in_sizes[3] / 4;

    float* out    = (float*)d_out;
    float* out0   = out;
    float* out1   = out + (size_t)P;
    float* outcls = out + (size_t)2 * P;      // one-hot region; clsT scratch first
    float* outbox = out + (size_t)82 * P;

    int tb = (P + 63) / 64;
    int pb = (P + 255) / 256;
    int seglen = (P + NSEG - 1) / NSEG;
    int gtiles = (N + GPB - 1) / GPB;
    dim3 gridA1(NSEG, gtiles);
    size_t candBytes = (size_t)N * NSEG * TOPK * sizeof(float2);
    size_t needWs = (size_t)P * 8 + candBytes + (size_t)N * 4 + 64;

    if (ws_size >= needWs) {
        // ws: count[P] | firstg[P] | cand | gorder[N]
        int*    count  = (int*)d_ws;
        int*    firstg = count + P;
        float2* cand   = (float2*)(firstg + P);
        int*    gorder = (int*)((char*)cand + candBytes);

        sortgt<<<1, 256, 0, stream>>>(label_gt, gorder, N);
        prep<<<tb, 256, 0, stream>>>((const float4*)cls_pred, outcls, count, firstg, P);
        phaseA1<<<gridA1, 512, 0, stream>>>(outcls, (const float4*)bbox_pred,
                                            (const float4*)bbox_gt, label_gt, gorder,
                                            cand, P, N, seglen);
        phaseA2<<<N, 512, 0, stream>>>(cand, count, firstg);
        phaseCF<<<pb, 256, 0, stream>>>((const float4*)bbox_pred, (const float4*)bbox_gt,
                                        label_gt, count, firstg, out0, out1,
                                        (float4*)outcls, (float4*)outbox, P, N);
    } else {
        // fallback: scratch inside outbox region (4P floats = P*16 bytes)
        int*    count  = (int*)outbox;
        int*    firstg = ((int*)outbox) + P;
        float2* cand   = (float2*)(((int*)outbox) + 2 * (size_t)P);
        int*    gorder = (int*)((char*)cand + candBytes);

        sortgt<<<1, 256, 0, stream>>>(label_gt, gorder, N);
        prep<<<tb, 256, 0, stream>>>((const float4*)cls_pred, outcls, count, firstg, P);
        phaseA1<<<gridA1, 512, 0, stream>>>(outcls, (const float4*)bbox_pred,
                                            (const float4*)bbox_gt, label_gt, gorder,
                                            cand, P, N, seglen);
        phaseA2<<<N, 512, 0, stream>>>(cand, count, firstg);
        phaseC1<<<pb, 256, 0, stream>>>((const float4*)bbox_pred, (const float4*)bbox_gt,
                                        label_gt, count, firstg, out0, out1, P, N);
        phaseC2<<<pb, 256, 0, stream>>>((const float4*)bbox_gt, label_gt, out0,
                                        outcls, outbox, P, N);
    }
}

// Round 6
// 221.460 us; speedup vs baseline: 1.9090x; 1.0518x over previous
//
#include <hip/hip_runtime.h>

#define TOPK 13
#define NCLS 80
#define EPSF 1e-9f
#define NSEG 32
#define GPB  8          // GTs per block (one per wave at selection time)
#define CAP3 512        // per-g candidate p-indices (avg ~190+16, 6-sigma ~290)
#define MCAP (64 * TOPK)  // merge scratch entries per wave

// ---------------------------------------------------------------------------
// sortgt: stable sort GT indices by (class, g) -> gorder. One 256-thread block.
// Same-class GTs grouped per block -> phase-2 cls gathers share cachelines.
// ---------------------------------------------------------------------------
__global__ __launch_bounds__(256) void sortgt(const int* __restrict__ lbl,
                                              int* __restrict__ gorder, int N) {
    __shared__ int key[256];
    int t = threadIdx.x;
    key[t] = (t < N) ? ((lbl[t] << 8) | t) : 0x7FFFFFFF;
    __syncthreads();
    for (int k = 2; k <= 256; k <<= 1) {
        for (int j = k >> 1; j >= 1; j >>= 1) {
            int ixj = t ^ j;
            if (ixj > t) {
                int a = key[t], b = key[ixj];
                bool up = ((t & k) == 0);
                if (up ? (a > b) : (a < b)) { key[t] = b; key[ixj] = a; }
            }
            __syncthreads();
        }
    }
    if (t < N) gorder[t] = key[t] & 0xFF;
}

// ---------------------------------------------------------------------------
// phaseA1: grid (NSEG, N/8), 512 threads.
// HOT: overlap-filter only (dx>0 && dy>0) -> append p to per-g LDS list.
// SPARSE: wave wv exactly evaluates g-slot wv's ~190 candidates (gather
// bboxp[p] + cls_pred[p*80+c], bit-exact metric), per-lane top-13 with
// (m desc, p asc) total order, LDS tree merge, write 13 to cand.
// Overflow (>CAP3) -> exact full rescan for that g (cold, never for this N).
// ---------------------------------------------------------------------------
__global__ __launch_bounds__(512, 4) void phaseA1(const float* __restrict__ cls,
                                                  const float4* __restrict__ bboxp,
                                                  const float4* __restrict__ bboxg,
                                                  const int* __restrict__ lbl,
                                                  const int* __restrict__ gorder,
                                                  float2* __restrict__ cand,
                                                  int P, int N, int seglen) {
#pragma clang fp contract(off)
    const int s = blockIdx.x, tile = blockIdx.y, t = threadIdx.x;
    const int wv = t >> 6, lane = t & 63;
    const int pstart = s * seglen;
    int pend = pstart + seglen; if (pend > P) pend = P;

    __shared__ int pbuf[GPB][CAP3];      // 16 KB
    __shared__ float2 mbuf[GPB][MCAP];   // 53.25 KB
    __shared__ int ctr[GPB];

    // GT boxes for the filter (indexed only by compile-time constants)
    float4 gb[GPB];
#pragma unroll
    for (int j = 0; j < GPB; j++) {
        int gi8 = tile * GPB + j;
        int gj = (gi8 < N) ? gorder[gi8] : -1;
        gb[j] = (gj >= 0) ? bboxg[gj] : make_float4(0.f, 0.f, 0.f, 0.f);
    }
    if (t < GPB) ctr[t] = 0;
    __syncthreads();

    // ---- HOT filter loop: ~16 VALU per (g,p) pair ----
    bool first = true;
    for (int p = pstart + t; p < pend; p += 512) {
        float4 pb = bboxp[p];
        bool force = first && (t < 16);
        first = false;
#pragma unroll
        for (int j = 0; j < GPB; j++) {
            float dx = fminf(gb[j].z, pb.z) - fmaxf(gb[j].x, pb.x);
            float dy = fminf(gb[j].w, pb.w) - fmaxf(gb[j].y, pb.y);
            bool want = ((dx > 0.0f) && (dy > 0.0f)) || force;
            if (want) {
                int slot = atomicAdd(&ctr[j], 1);
                if (slot < CAP3) pbuf[j][slot] = p;
            }
        }
    }
    __syncthreads();

    // ---- SPARSE exact evaluation: wave wv owns g-slot wv ----
    const int gi8 = tile * GPB + wv;
    const bool myValid = gi8 < N;
    const int gj = myValid ? gorder[gi8] : 0;
    const float4 gbw = bboxg[gj];
    const float gaw = fmaxf(gbw.z - gbw.x, 0.0f) * fmaxf(gbw.w - gbw.y, 0.0f);
    const int cidx = lbl[gj] - 1;
    const int rawtotal = ctr[wv];

    float v[TOPK]; int id[TOPK];
#pragma unroll
    for (int k = 0; k < TOPK; k++) { v[k] = -1.0f; id[k] = 0x7FFFFFFF; }

    auto ins = [&](float m, int p) {
        bool b12 = (m > v[TOPK - 1]) || (m == v[TOPK - 1] && p < id[TOPK - 1]);
        if (b12) {
#pragma unroll
            for (int k = TOPK - 1; k >= 1; k--) {
                bool a = (m > v[k - 1]) || (m == v[k - 1] && p < id[k - 1]);
                bool b = (m > v[k]) || (m == v[k] && p < id[k]);
                float nv = a ? v[k - 1] : (b ? m : v[k]);
                int   ni = a ? id[k - 1] : (b ? p : id[k]);
                v[k] = nv; id[k] = ni;
            }
            bool a0 = (m > v[0]) || (m == v[0] && p < id[0]);
            if (a0) { v[0] = m; id[0] = p; }
        }
    };

    if (rawtotal <= CAP3) {
        for (int e = lane; e < rawtotal; e += 64) {
            int p = pbuf[wv][e];
            float4 pb = bboxp[p];                       // sparse gather
            float sc = cls[(size_t)p * NCLS + cidx];    // sparse gather
            float pa = fmaxf(pb.z - pb.x, 0.0f) * fmaxf(pb.w - pb.y, 0.0f);
            float xx1 = fmaxf(gbw.x, pb.x), yy1 = fmaxf(gbw.y, pb.y);
            float xx2 = fminf(gbw.z, pb.z), yy2 = fminf(gbw.w, pb.w);
            float inter = fmaxf(xx2 - xx1, 0.0f) * fmaxf(yy2 - yy1, 0.0f);
            float iou = inter / (((gaw + pa) - inter) + EPSF);
            float i2 = iou * iou;
            float m = sc * ((i2 * i2) * i2);
            ins(m, p);
        }
    } else if (myValid) {
        // overflow: exact full rescan for this g (cold path)
        for (int p = pstart + lane; p < pend; p += 64) {
            float4 pb = bboxp[p];
            float sc = cls[(size_t)p * NCLS + cidx];
            float pa = fmaxf(pb.z - pb.x, 0.0f) * fmaxf(pb.w - pb.y, 0.0f);
            float xx1 = fmaxf(gbw.x, pb.x), yy1 = fmaxf(gbw.y, pb.y);
            float xx2 = fminf(gbw.z, pb.z), yy2 = fminf(gbw.w, pb.w);
            float inter = fmaxf(xx2 - xx1, 0.0f) * fmaxf(yy2 - yy1, 0.0f);
            float iou = inter / (((gaw + pa) - inter) + EPSF);
            float i2 = iou * iou;
            float m = sc * ((i2 * i2) * i2);
            ins(m, p);
        }
    }

    // ---- per-wave LDS tree merge (distinct mbuf region per wave) ----
    float2* wl = mbuf[wv];
#pragma unroll
    for (int k = 0; k < TOPK; k++)
        wl[lane * TOPK + k] = make_float2(v[k], __int_as_float(id[k]));
    __syncthreads();
    for (int str = 32; str >= 1; str >>= 1) {
        if (lane < str) {
            float2 merged[TOPK];
            int a = 0, b = 0;
            const int ba = lane * TOPK, bb = (lane + str) * TOPK;
#pragma unroll
            for (int k = 0; k < TOPK; k++) {
                float2 fa = wl[ba + a], fb = wl[bb + b];
                int ia = __float_as_int(fa.y), ib = __float_as_int(fb.y);
                bool takeA = (fa.x > fb.x) || (fa.x == fb.x && ia < ib);
                merged[k] = takeA ? fa : fb;
                a += takeA; b += !takeA;
            }
#pragma unroll
            for (int k = 0; k < TOPK; k++) wl[ba + k] = merged[k];
        }
        __syncthreads();
    }
    if (lane < TOPK && myValid)
        cand[((size_t)gj * NSEG + s) * TOPK + lane] = wl[lane];
}

// ---------------------------------------------------------------------------
// phaseA2: per GT merge NSEG*13=416 candidates -> exact global top-13 via a
// 512-element bitonic sort, then scatter count/firstg atomics if max > eps.
// ---------------------------------------------------------------------------
__global__ __launch_bounds__(512) void phaseA2(const float2* __restrict__ cand,
                                               int* __restrict__ count,
                                               int* __restrict__ firstg) {
    const int g = blockIdx.x;
    const int t = threadIdx.x;
    const int M = NSEG * TOPK;  // 416
    __shared__ float cv[512];
    __shared__ int   ci[512];
    if (t < M) {
        float2 e = cand[(size_t)g * M + t];
        cv[t] = e.x; ci[t] = __float_as_int(e.y);
    } else {
        cv[t] = -1.0f; ci[t] = 0x7FFFFFFF;
    }
    __syncthreads();
    for (int k = 2; k <= 512; k <<= 1) {
        for (int j = k >> 1; j >= 1; j >>= 1) {
            int ixj = t ^ j;
            if (ixj > t) {
                float va = cv[t], vb = cv[ixj];
                int   ia = ci[t], ib = ci[ixj];
                bool aBeforeB = (va > vb) || (va == vb && ia < ib);
                bool dirFwd = ((t & k) == 0);
                bool doswap = dirFwd ? !aBeforeB : aBeforeB;
                if (doswap) { cv[t] = vb; ci[t] = ib; cv[ixj] = va; ci[ixj] = ia; }
            }
            __syncthreads();
        }
    }
    if (t < TOPK && cv[0] > EPSF) {
        int pi = ci[t];
        atomicAdd(&count[pi], 1);
        atomicMin(&firstg[pi], g);
    }
}

// ---------------------------------------------------------------------------
// phaseCF (ws path): fused resolve + all outputs, dense coalesced writes.
// ---------------------------------------------------------------------------
__global__ __launch_bounds__(256) void phaseCF(const float4* __restrict__ bboxp,
                                               const float4* __restrict__ bboxg,
                                               const int* __restrict__ lbl,
                                               const int* __restrict__ count,
                                               const int* __restrict__ firstg,
                                               float* __restrict__ out0,
                                               float* __restrict__ out1,
                                               float4* __restrict__ outcls4,
                                               float4* __restrict__ outbox4, int P, int N) {
#pragma clang fp contract(off)
    __shared__ float4 gbS[256];
    __shared__ int glS[256];
    __shared__ int gil[256];
    __shared__ int clsl[256];
    int t = threadIdx.x;
    if (t < N) { gbS[t] = bboxg[t]; glS[t] = lbl[t]; }
    __syncthreads();
    int p0 = blockIdx.x * 256;
    int nloc = P - p0; if (nloc > 256) nloc = 256;
    if (t < nloc) {
        int p = p0 + t;
        int cnt = count[p];
        int gi = 0, pos = 0;
        if (cnt == 1) { gi = firstg[p]; pos = 1; }
        else if (cnt > 1) {
            float4 pb = bboxp[p];
            float pa = fmaxf(pb.z - pb.x, 0.0f) * fmaxf(pb.w - pb.y, 0.0f);
            float best = -1.0f;
            for (int g = 0; g < N; g++) {
                float4 g4 = gbS[g];
                float gar = fmaxf(g4.z - g4.x, 0.0f) * fmaxf(g4.w - g4.y, 0.0f);
                float xx1 = fmaxf(g4.x, pb.x), yy1 = fmaxf(g4.y, pb.y);
                float xx2 = fminf(g4.z, pb.z), yy2 = fminf(g4.w, pb.w);
                float inter = fmaxf(xx2 - xx1, 0.0f) * fmaxf(yy2 - yy1, 0.0f);
                float iou = inter / (((gar + pa) - inter) + EPSF);
                if (iou > best) { best = iou; gi = g; }   // strict > == first-max
            }
            pos = 1;
        }
        out0[p] = (float)gi;
        out1[p] = pos ? (float)glS[gi] : 0.0f;
        gil[t] = gi;
        clsl[t] = glS[gi] - 1;
        outbox4[p] = gbS[gi];
    }
    __syncthreads();
    for (int f = t; f < nloc * 20; f += 256) {
        int pl = f / 20, q = f - pl * 20;
        int cl = clsl[pl], c0 = q * 4;
        float4 vv = make_float4(c0 == cl ? 1.0f : 0.0f, c0 + 1 == cl ? 1.0f : 0.0f,
                                c0 + 2 == cl ? 1.0f : 0.0f, c0 + 3 == cl ? 1.0f : 0.0f);
        outcls4[(size_t)p0 * 20 + f] = vv;
    }
}

// ---------------------------------------------------------------------------
// Fallback path (small ws): scratch aliases the bbox-output region, so split
// resolve (C1) and dense writes (C2) into separate launches.
// ---------------------------------------------------------------------------
__global__ __launch_bounds__(256) void phaseC1(const float4* __restrict__ bboxp,
                                               const float4* __restrict__ bboxg,
                                               const int* __restrict__ lbl,
                                               const int* __restrict__ count,
                                               const int* __restrict__ firstg,
                                               float* __restrict__ out0,
                                               float* __restrict__ out1, int P, int N) {
#pragma clang fp contract(off)
    __shared__ float4 gbS[256];
    __shared__ int glS[256];
    if (threadIdx.x < (unsigned)N) {
        gbS[threadIdx.x] = bboxg[threadIdx.x];
        glS[threadIdx.x] = lbl[threadIdx.x];
    }
    __syncthreads();
    int p = blockIdx.x * 256 + threadIdx.x;
    if (p >= P) return;
    int cnt = count[p];
    int gi = 0, pos = 0;
    if (cnt == 1) { gi = firstg[p]; pos = 1; }
    else if (cnt > 1) {
        float4 pb = bboxp[p];
        float pa = fmaxf(pb.z - pb.x, 0.0f) * fmaxf(pb.w - pb.y, 0.0f);
        float best = -1.0f;
        for (int g = 0; g < N; g++) {
            float4 g4 = gbS[g];
            float gar = fmaxf(g4.z - g4.x, 0.0f) * fmaxf(g4.w - g4.y, 0.0f);
            float xx1 = fmaxf(g4.x, pb.x), yy1 = fmaxf(g4.y, pb.y);
            float xx2 = fminf(g4.z, pb.z), yy2 = fminf(g4.w, pb.w);
            float inter = fmaxf(xx2 - xx1, 0.0f) * fmaxf(yy2 - yy1, 0.0f);
            float iou = inter / (((gar + pa) - inter) + EPSF);
            if (iou > best) { best = iou; gi = g; }
        }
        pos = 1;
    }
    out0[p] = (float)gi;
    out1[p] = pos ? (float)glS[gi] : 0.0f;
}

__global__ __launch_bounds__(256) void phaseC2(const float4* __restrict__ bboxg,
                                               const int* __restrict__ lbl,
                                               const float* __restrict__ out0,
                                               float* __restrict__ outcls,
                                               float* __restrict__ outbox, int P, int N) {
    __shared__ float gbb[256 * 4];
    __shared__ int glS[256];
    __shared__ int clsl[256];
    __shared__ int gil[256];
    int tid = threadIdx.x;
    if (tid < N) {
        float4 b = bboxg[tid];
        gbb[tid * 4 + 0] = b.x; gbb[tid * 4 + 1] = b.y;
        gbb[tid * 4 + 2] = b.z; gbb[tid * 4 + 3] = b.w;
        glS[tid] = lbl[tid];
    }
    __syncthreads();
    int p0 = blockIdx.x * 256;
    int nloc = P - p0; if (nloc > 256) nloc = 256;
    if (tid < nloc) {
        int gi = (int)out0[p0 + tid];
        gil[tid] = gi;
        clsl[tid] = glS[gi] - 1;
    }
    __syncthreads();
    for (int f = tid; f < nloc * NCLS; f += 256) {
        int pl = f / NCLS;
        int c  = f - pl * NCLS;
        outcls[(size_t)p0 * NCLS + f] = (c == clsl[pl]) ? 1.0f : 0.0f;
    }
    for (int f = tid; f < nloc * 4; f += 256) {
        int pl = f >> 2, k = f & 3;
        outbox[(size_t)p0 * 4 + f] = gbb[gil[pl] * 4 + k];
    }
}

extern "C" void kernel_launch(void* const* d_in, const int* in_sizes, int n_in,
                              void* d_out, int out_size, void* d_ws, size_t ws_size,
                              hipStream_t stream) {
    const float* cls_pred  = (const float*)d_in[0];
    const float* bbox_pred = (const float*)d_in[1];
    const int*   label_gt  = (const int*)d_in[2];
    const float* bbox_gt   = (const float*)d_in[3];
    int P = in_sizes[1] / 4;
    int N = in_sizes[3] / 4;

    float* out    = (float*)d_out;
    float* out0   = out;
    float* out1   = out + (size_t)P;
    float* outcls = out + (size_t)2 * P;
    float* outbox = out + (size_t)82 * P;

    int pb = (P + 255) / 256;
    int seglen = (P + NSEG - 1) / NSEG;
    int gtiles = (N + GPB - 1) / GPB;
    dim3 gridA1(NSEG, gtiles);
    size_t candBytes = (size_t)N * NSEG * TOPK * sizeof(float2);
    size_t needWs = (size_t)P * 8 + candBytes + (size_t)N * 4 + 64;

    if (ws_size >= needWs) {
        // ws: count[P] | firstg[P] | cand | gorder[N]
        int*    count  = (int*)d_ws;
        int*    firstg = count + P;
        float2* cand   = (float2*)(firstg + P);
        int*    gorder = (int*)((char*)cand + candBytes);

        hipMemsetAsync(count, 0, (size_t)P * sizeof(int), stream);
        hipMemsetAsync(firstg, 0x7F, (size_t)P * sizeof(int), stream);
        sortgt<<<1, 256, 0, stream>>>(label_gt, gorder, N);
        phaseA1<<<gridA1, 512, 0, stream>>>(cls_pred, (const float4*)bbox_pred,
                                            (const float4*)bbox_gt, label_gt, gorder,
                                            cand, P, N, seglen);
        phaseA2<<<N, 512, 0, stream>>>(cand, count, firstg);
        phaseCF<<<pb, 256, 0, stream>>>((const float4*)bbox_pred, (const float4*)bbox_gt,
                                        label_gt, count, firstg, out0, out1,
                                        (float4*)outcls, (float4*)outbox, P, N);
    } else {
        // fallback: scratch inside outbox region; split C1/C2
        int*    count  = (int*)outbox;
        int*    firstg = ((int*)outbox) + P;
        float2* cand   = (float2*)(((int*)outbox) + 2 * (size_t)P);
        int*    gorder = (int*)((char*)cand + candBytes);

        hipMemsetAsync(count, 0, (size_t)P * sizeof(int), stream);
        hipMemsetAsync(firstg, 0x7F, (size_t)P * sizeof(int), stream);
        sortgt<<<1, 256, 0, stream>>>(label_gt, gorder, N);
        phaseA1<<<gridA1, 512, 0, stream>>>(cls_pred, (const float4*)bbox_pred,
                                            (const float4*)bbox_gt, label_gt, gorder,
                                            cand, P, N, seglen);
        phaseA2<<<N, 512, 0, stream>>>(cand, count, firstg);
        phaseC1<<<pb, 256, 0, stream>>>((const float4*)bbox_pred, (const float4*)bbox_gt,
                                        label_gt, count, firstg, out0, out1, P, N);
        phaseC2<<<pb, 256, 0, stream>>>((const float4*)bbox_gt, label_gt, out0,
                                        outcls, outbox, P, N);
    }
}